// Round 1
// 4105.063 us; speedup vs baseline: 1.3940x; 1.3940x over previous
//
#include <hip/hip_runtime.h>
#include <math.h>

#define DIMX 768
#define FFX  3072
#define SX   6
#define VX   32000
#define BX   2
#define TX   1024
#define BT   (BX*TX)
#define LDK  40   // LDS row stride (bf16 elems) for 32-wide K tiles, padded

typedef __bf16 bf16x8 __attribute__((ext_vector_type(8)));
typedef __bf16 bf16x4 __attribute__((ext_vector_type(4)));
typedef float  f32x4  __attribute__((ext_vector_type(4)));

__device__ __forceinline__ float gelu_f(float x){
    float x3 = x*x*x;
    return 0.5f*x*(1.0f + tanhf(0.7978845608028654f*(x + 0.044715f*x3)));
}
__device__ __forceinline__ float softplus_f(float x){
    return fmaxf(x,0.0f) + log1pf(expf(-fabsf(x)));
}

__device__ __forceinline__ float block_reduce_sum(float v, volatile float* sbuf){
    #pragma unroll
    for(int off=32; off>0; off>>=1) v += __shfl_down(v, off, 64);
    int wid = threadIdx.x >> 6, lane = threadIdx.x & 63;
    __syncthreads();
    if(lane==0) sbuf[wid] = v;
    __syncthreads();
    return sbuf[0]+sbuf[1]+sbuf[2]+sbuf[3];
}

// ---------------- embed + pi init ----------------
__global__ void k_embed(const int* __restrict__ x, const float* __restrict__ emb,
                        const float* __restrict__ pos, float* __restrict__ h,
                        float* __restrict__ pi){
    int tok = blockIdx.x;
    int t = tok % TX;
    int id = x[tok];
    const float* er = emb + (long)id*DIMX;
    const float* pr = pos + (long)t*DIMX;
    float* hr = h + (long)tok*DIMX;
    for(int d=threadIdx.x; d<DIMX; d+=blockDim.x) hr[d] = er[d] + pr[d];
    if(threadIdx.x < SX) pi[tok*SX+threadIdx.x] = (threadIdx.x==2)?1.0f:0.0f;
}

// ---------------- expert list init (step 0: all tokens -> expert 2) ----------------
__global__ void k_init_lists(int* __restrict__ gidx, int* __restrict__ cnt){
    int tid = blockIdx.x*blockDim.x + threadIdx.x;
    if(tid < SX*BT) gidx[tid] = (tid/BT == 2) ? (tid % BT) : BT;
    if(tid < SX) cnt[tid] = (tid==2) ? BT : 0;
}
__global__ void k_fill_lists(int* __restrict__ gidx, int* __restrict__ cnt){
    int tid = blockIdx.x*blockDim.x + threadIdx.x;
    if(tid < SX*BT) gidx[tid] = BT;
    if(tid < SX) cnt[tid] = 0;
}

// ---------------- fp32 -> bf16 elementwise (emb_w for logits) ----------------
__global__ void k_cvt_bf16(const float* __restrict__ in, __bf16* __restrict__ out, long n){
    long i = ((long)blockIdx.x*blockDim.x + threadIdx.x)*4;
    if(i+3 < n){
        float4 v = *(const float4*)&in[i];
        bf16x4 o;
        o[0]=(__bf16)v.x; o[1]=(__bf16)v.y; o[2]=(__bf16)v.z; o[3]=(__bf16)v.w;
        *(bf16x4*)&out[i] = o;
    }
}

// ---------------- transpose + hi/lo split of a weight: in [K][N] fp32 -> out [N][K] bf16 hi/lo ----
__global__ __launch_bounds__(256) void k_tsplit(const float* __restrict__ in,
        __bf16* __restrict__ oh, __bf16* __restrict__ ol, int K, int N){
    __shared__ float t[32][33];
    int k0 = blockIdx.x*32, n0 = blockIdx.y*32;
    int tid = threadIdx.x;
    #pragma unroll
    for(int i=0;i<4;i++){
        int r = (tid>>5) + i*8, cc = tid & 31;
        t[r][cc] = in[(long)(k0+r)*N + n0 + cc];
    }
    __syncthreads();
    int r2 = tid & 31, q = tid >> 5;   // r2: n-local, q: k-quad
    bf16x4 h4, l4;
    #pragma unroll
    for(int e=0;e<4;e++){
        float v = t[q*4+e][r2];
        __bf16 hv = (__bf16)v;
        h4[e] = hv;
        l4[e] = (__bf16)(v - (float)hv);
    }
    long o = (long)(n0 + r2)*K + k0 + q*4;
    *(bf16x4*)&oh[o] = h4;
    *(bf16x4*)&ol[o] = l4;
}

// ---------------- unified split-bf16 MFMA GEMM ----------------
// C = act(A @ B + bias) with A fp32 (split on the fly) or pre-split bf16 pairs,
// B pre-split+transposed [N][K] bf16 hi/lo. 3-pass Dekker: AhBh + AlBh + AhBl.
// GATHER: A rows gathered via gidx. OUT: 0 = fp32 store, 1 = bf16 hi/lo pair store,
// 2 = scatter-add C[gid[m]] += pi[gid[m],s] * v.
template<int BM, int BN, int GATHER, int ASRC, int ACT, int OUT>
__global__ __launch_bounds__(256) void k_gemm_mfma(
    const float* __restrict__ A,
    const __bf16* __restrict__ Ahg, const __bf16* __restrict__ Alg,
    const __bf16* __restrict__ Bh, const __bf16* __restrict__ Bl,
    const float* __restrict__ bias, float* __restrict__ C,
    __bf16* __restrict__ Ch, __bf16* __restrict__ Cl,
    const float* __restrict__ pi, const int* __restrict__ gidx,
    const int* __restrict__ cnt, int s, int N, int K)
{
    int bm = blockIdx.y * BM, bn = blockIdx.x * BN;
    int c = BT;
    const int* gid = nullptr;
    if(GATHER || OUT==2){
        c = cnt[s];
        if(bm >= c) return;
        gid = gidx + s*BT;
    }

    __shared__ __bf16 AhS[BM*LDK];
    __shared__ __bf16 AlS[BM*LDK];
    __shared__ __bf16 BhS[BN*LDK];
    __shared__ __bf16 BlS[BN*LDK];

    int tid = threadIdx.x;
    int lane = tid & 63, wave = tid >> 6, ln = lane & 15, quad = lane >> 4;
    constexpr int WGM = BM/64;       // wave-grid rows (1 or 2)
    constexpr int WGN = 4/WGM;       // wave-grid cols (4 or 2)
    constexpr int WM  = BM/WGM;      // 64
    constexpr int WN  = BN/WGN;      // 32 or 64
    constexpr int MR  = WM/16;       // 4
    constexpr int NR  = WN/16;       // 2 or 4
    int wm = (wave/WGN)*WM, wn = (wave%WGN)*WN;

    f32x4 acc[MR][NR];
    #pragma unroll
    for(int i=0;i<MR;i++){
        #pragma unroll
        for(int j=0;j<NR;j++){
            f32x4 z = {0.0f,0.0f,0.0f,0.0f};
            acc[i][j] = z;
        }
    }

    constexpr int ACH = (BM*32/8)/256;   // A chunks per thread (1 or 2)
    constexpr int BCH = (BN*32/8)/256;   // B chunks per thread (2 for BN=128)
    long arow[ACH];
    #pragma unroll
    for(int i=0;i<ACH;i++){
        int row = (tid + 256*i) >> 2;
        int gr = bm + row;
        if(GATHER){ int g = gid[gr]; gr = (g < BT) ? g : 0; }
        arow[i] = (long)gr * K;
    }

    for(int k0=0; k0<K; k0+=32){
        #pragma unroll
        for(int i=0;i<ACH;i++){
            int idx = tid + 256*i;
            int row = idx >> 2, c8 = idx & 3;
            if(ASRC==0){
                const float* src = A + arow[i] + k0 + c8*8;
                float4 v0 = *(const float4*)src;
                float4 v1 = *(const float4*)(src+4);
                float vs[8] = {v0.x,v0.y,v0.z,v0.w,v1.x,v1.y,v1.z,v1.w};
                bf16x8 h8, l8;
                #pragma unroll
                for(int e=0;e<8;e++){
                    __bf16 hv = (__bf16)vs[e];
                    h8[e] = hv;
                    l8[e] = (__bf16)(vs[e] - (float)hv);
                }
                *(bf16x8*)&AhS[row*LDK + c8*8] = h8;
                *(bf16x8*)&AlS[row*LDK + c8*8] = l8;
            } else {
                *(bf16x8*)&AhS[row*LDK + c8*8] = *(const bf16x8*)&Ahg[arow[i] + k0 + c8*8];
                *(bf16x8*)&AlS[row*LDK + c8*8] = *(const bf16x8*)&Alg[arow[i] + k0 + c8*8];
            }
        }
        #pragma unroll
        for(int i=0;i<BCH;i++){
            int idx = tid + 256*i;
            int row = idx >> 2, c8 = idx & 3;
            long o = (long)(bn + row)*K + k0 + c8*8;
            *(bf16x8*)&BhS[row*LDK + c8*8] = *(const bf16x8*)&Bh[o];
            *(bf16x8*)&BlS[row*LDK + c8*8] = *(const bf16x8*)&Bl[o];
        }
        __syncthreads();
        bf16x8 ah[MR], al[MR], bh[NR], bl[NR];
        #pragma unroll
        for(int i=0;i<MR;i++){
            ah[i] = *(const bf16x8*)&AhS[(wm+i*16+ln)*LDK + quad*8];
            al[i] = *(const bf16x8*)&AlS[(wm+i*16+ln)*LDK + quad*8];
        }
        #pragma unroll
        for(int j=0;j<NR;j++){
            bh[j] = *(const bf16x8*)&BhS[(wn+j*16+ln)*LDK + quad*8];
            bl[j] = *(const bf16x8*)&BlS[(wn+j*16+ln)*LDK + quad*8];
        }
        #pragma unroll
        for(int i=0;i<MR;i++)
            #pragma unroll
            for(int j=0;j<NR;j++)
                acc[i][j] = __builtin_amdgcn_mfma_f32_16x16x32_bf16(ah[i], bh[j], acc[i][j], 0,0,0);
        #pragma unroll
        for(int i=0;i<MR;i++)
            #pragma unroll
            for(int j=0;j<NR;j++)
                acc[i][j] = __builtin_amdgcn_mfma_f32_16x16x32_bf16(al[i], bh[j], acc[i][j], 0,0,0);
        #pragma unroll
        for(int i=0;i<MR;i++)
            #pragma unroll
            for(int j=0;j<NR;j++)
                acc[i][j] = __builtin_amdgcn_mfma_f32_16x16x32_bf16(ah[i], bl[j], acc[i][j], 0,0,0);
        __syncthreads();
    }

    #pragma unroll
    for(int i=0;i<MR;i++){
        #pragma unroll
        for(int j=0;j<NR;j++){
            int n = bn + wn + j*16 + ln;
            float bv = bias ? bias[n] : 0.0f;
            #pragma unroll
            for(int r=0;r<4;r++){
                int ml = wm + i*16 + quad*4 + r;
                float v = acc[i][j][r] + bv;
                if(ACT==1) v = gelu_f(v);
                else if(ACT==2) v = softplus_f(v) + 0.1f;
                if(OUT==0){
                    C[(long)(bm+ml)*N + n] = v;
                } else if(OUT==1){
                    long o = (long)(bm+ml)*N + n;
                    __bf16 hv = (__bf16)v;
                    Ch[o] = hv;
                    Cl[o] = (__bf16)(v - (float)hv);
                } else {
                    int m = bm + ml;
                    int tok = (m < c) ? gid[m] : BT;
                    float p = (m < c && tok < BT) ? pi[tok*SX + s] : 0.0f;
                    if(tok > BT) tok = BT;
                    C[(long)tok*N + n] += p * v;
                }
            }
        }
    }
}

// ---------------- generic fp32 GEMM (NN), C = act(A@B + bias)  [fallback path] ----------------
template<int ACT>
__global__ void k_gemm_nn(const float* __restrict__ A, const float* __restrict__ B,
                          const float* __restrict__ bias, float* __restrict__ C,
                          int M, int N, int K){
    __shared__ float As[16][68];
    __shared__ float Bs[16][68];
    int tx = threadIdx.x & 15, ty = threadIdx.x >> 4;
    int bm = blockIdx.y * 64, bn = blockIdx.x * 64;
    float acc[4][4] = {};
    int la_c = threadIdx.x & 15;
    int la_r = threadIdx.x >> 4;
    int lb_r = threadIdx.x >> 6;
    int lb_c = threadIdx.x & 63;
    for(int k0=0; k0<K; k0+=16){
        #pragma unroll
        for(int i=0;i<4;i++)
            As[la_c][la_r + 16*i] = A[(long)(bm + la_r + 16*i)*K + k0 + la_c];
        #pragma unroll
        for(int i=0;i<4;i++)
            Bs[lb_r + 4*i][lb_c] = B[(long)(k0 + lb_r + 4*i)*N + bn + lb_c];
        __syncthreads();
        #pragma unroll
        for(int k=0;k<16;k++){
            float4 a4 = *(const float4*)&As[k][ty*4];
            float4 b4 = *(const float4*)&Bs[k][tx*4];
            float av[4]={a4.x,a4.y,a4.z,a4.w}, bv[4]={b4.x,b4.y,b4.z,b4.w};
            #pragma unroll
            for(int i=0;i<4;i++)
                #pragma unroll
                for(int j=0;j<4;j++)
                    acc[i][j] += av[i]*bv[j];
        }
        __syncthreads();
    }
    #pragma unroll
    for(int i=0;i<4;i++){
        int m = bm + ty*4 + i;
        #pragma unroll
        for(int j=0;j<4;j++){
            int n = bn + tx*4 + j;
            float v = acc[i][j] + (bias ? bias[n] : 0.0f);
            if(ACT==1) v = gelu_f(v);
            else if(ACT==2) v = softplus_f(v) + 0.1f;
            C[(long)m*N + n] = v;
        }
    }
}

// ---------------- gathered bank GEMM 1 (fallback) ----------------
__global__ void k_gemm_g1(const float* __restrict__ A, const float* __restrict__ B,
                          const float* __restrict__ bias, float* __restrict__ C,
                          const int* __restrict__ gidx, const int* __restrict__ cnt,
                          int s, int N, int K){
    int c = cnt[s];
    int bm = blockIdx.y * 64;
    if(bm >= c) return;
    const int* gid = gidx + s*BT;
    __shared__ float As[16][68];
    __shared__ float Bs[16][68];
    int tx = threadIdx.x & 15, ty = threadIdx.x >> 4;
    int bn = blockIdx.x * 64;
    float acc[4][4] = {};
    int la_c = threadIdx.x & 15;
    int la_r = threadIdx.x >> 4;
    int lb_r = threadIdx.x >> 6;
    int lb_c = threadIdx.x & 63;
    int rowA[4];
    #pragma unroll
    for(int i=0;i<4;i++){
        int tok = gid[bm + la_r + 16*i];
        rowA[i] = (tok < BT) ? tok : 0;
    }
    for(int k0=0; k0<K; k0+=16){
        #pragma unroll
        for(int i=0;i<4;i++)
            As[la_c][la_r + 16*i] = A[(long)rowA[i]*K + k0 + la_c];
        #pragma unroll
        for(int i=0;i<4;i++)
            Bs[lb_r + 4*i][lb_c] = B[(long)(k0 + lb_r + 4*i)*N + bn + lb_c];
        __syncthreads();
        #pragma unroll
        for(int k=0;k<16;k++){
            float4 a4 = *(const float4*)&As[k][ty*4];
            float4 b4 = *(const float4*)&Bs[k][tx*4];
            float av[4]={a4.x,a4.y,a4.z,a4.w}, bv[4]={b4.x,b4.y,b4.z,b4.w};
            #pragma unroll
            for(int i=0;i<4;i++)
                #pragma unroll
                for(int j=0;j<4;j++)
                    acc[i][j] += av[i]*bv[j];
        }
        __syncthreads();
    }
    #pragma unroll
    for(int i=0;i<4;i++){
        int m = bm + ty*4 + i;
        #pragma unroll
        for(int j=0;j<4;j++){
            int n = bn + tx*4 + j;
            C[(long)m*N + n] = gelu_f(acc[i][j] + bias[n]);
        }
    }
}

// ---------------- gathered bank GEMM 2 (fallback) ----------------
__global__ void k_gemm_g2(const float* __restrict__ A, const float* __restrict__ B,
                          const float* __restrict__ bias, float* __restrict__ C,
                          const float* __restrict__ pi, const int* __restrict__ gidx,
                          const int* __restrict__ cnt, int s, int N, int K){
    int c = cnt[s];
    int bm = blockIdx.y * 64;
    if(bm >= c) return;
    const int* gid = gidx + s*BT;
    __shared__ float As[16][68];
    __shared__ float Bs[16][68];
    int tx = threadIdx.x & 15, ty = threadIdx.x >> 4;
    int bn = blockIdx.x * 64;
    float acc[4][4] = {};
    int la_c = threadIdx.x & 15;
    int la_r = threadIdx.x >> 4;
    int lb_r = threadIdx.x >> 6;
    int lb_c = threadIdx.x & 63;
    for(int k0=0; k0<K; k0+=16){
        #pragma unroll
        for(int i=0;i<4;i++)
            As[la_c][la_r + 16*i] = A[(long)(bm + la_r + 16*i)*K + k0 + la_c];
        #pragma unroll
        for(int i=0;i<4;i++)
            Bs[lb_r + 4*i][lb_c] = B[(long)(k0 + lb_r + 4*i)*N + bn + lb_c];
        __syncthreads();
        #pragma unroll
        for(int k=0;k<16;k++){
            float4 a4 = *(const float4*)&As[k][ty*4];
            float4 b4 = *(const float4*)&Bs[k][tx*4];
            float av[4]={a4.x,a4.y,a4.z,a4.w}, bv[4]={b4.x,b4.y,b4.z,b4.w};
            #pragma unroll
            for(int i=0;i<4;i++)
                #pragma unroll
                for(int j=0;j<4;j++)
                    acc[i][j] += av[i]*bv[j];
        }
        __syncthreads();
    }
    #pragma unroll
    for(int i=0;i<4;i++){
        int m = bm + ty*4 + i;
        int tok = gid[m];
        float p = (m < c) ? pi[tok*SX + s] : 0.0f;
        #pragma unroll
        for(int j=0;j<4;j++){
            int n = bn + tx*4 + j;
            long ci = (long)tok*N + n;
            C[ci] += p * (acc[i][j] + bias[n]);
        }
    }
}

// ---------------- logits: bf16 MFMA NT GEMM, C = alpha * A @ B^T ----------------
// Grid swapped: blockIdx.x = row-block (16), blockIdx.y = col-block (250) so that
// consecutive blocks share one 196KB B tile -> L2-resident B reuse.
__global__ void k_logits_mfma(const float* __restrict__ A, const __bf16* __restrict__ Bw,
                              float* __restrict__ C, float alpha){
    __shared__ __bf16 Ah[128*LDK];
    __shared__ __bf16 Bh[128*LDK];
    int tid = threadIdx.x;
    int wave = tid>>6, lane = tid&63, ln = lane&15, quad = lane>>4;
    int bm = blockIdx.x*128, bn = blockIdx.y*128;
    int wm = (wave>>1)*64, wn = (wave&1)*64;
    f32x4 zero = {0.0f,0.0f,0.0f,0.0f};
    f32x4 acc[4][4];
    #pragma unroll
    for(int i=0;i<4;i++)
        #pragma unroll
        for(int j=0;j<4;j++) acc[i][j] = zero;
    for(int k0=0; k0<DIMX; k0+=32){
        #pragma unroll
        for(int i=0;i<4;i++){
            int idx = tid + 256*i;
            int row = idx>>3, c4 = idx&7;
            float4 v = *(const float4*)&A[(long)(bm+row)*DIMX + k0 + c4*4];
            bf16x4 o;
            o[0]=(__bf16)v.x; o[1]=(__bf16)v.y; o[2]=(__bf16)v.z; o[3]=(__bf16)v.w;
            *(bf16x4*)&Ah[row*LDK + c4*4] = o;
        }
        #pragma unroll
        for(int i=0;i<2;i++){
            int idx = tid + 256*i;
            int row = idx>>2, c8 = idx&3;
            bf16x8 v = *(const bf16x8*)&Bw[(long)(bn+row)*DIMX + k0 + c8*8];
            *(bf16x8*)&Bh[row*LDK + c8*8] = v;
        }
        __syncthreads();
        bf16x8 af[4], bfr[4];
        #pragma unroll
        for(int i=0;i<4;i++) af[i]  = *(const bf16x8*)&Ah[(wm+i*16+ln)*LDK + quad*8];
        #pragma unroll
        for(int j=0;j<4;j++) bfr[j] = *(const bf16x8*)&Bh[(wn+j*16+ln)*LDK + quad*8];
        #pragma unroll
        for(int i=0;i<4;i++)
            #pragma unroll
            for(int j=0;j<4;j++)
                acc[i][j] = __builtin_amdgcn_mfma_f32_16x16x32_bf16(af[i], bfr[j], acc[i][j], 0,0,0);
        __syncthreads();
    }
    #pragma unroll
    for(int i=0;i<4;i++){
        #pragma unroll
        for(int j=0;j<4;j++){
            #pragma unroll
            for(int r=0;r<4;r++){
                int m = bm + wm + i*16 + quad*4 + r;
                int n = bn + wn + j*16 + ln;
                C[(long)m*VX + n] = alpha * acc[i][j][r];
            }
        }
    }
}

// ---------------- layernorm ----------------
__global__ void k_ln(const float* __restrict__ in, float* __restrict__ out,
                     const float* __restrict__ g, const float* __restrict__ b){
    int tok = blockIdx.x;
    const float* r = in + (long)tok*DIMX;
    __shared__ float row[DIMX];
    __shared__ float sbuf[4];
    float lsum = 0;
    for(int d=threadIdx.x; d<DIMX; d+=blockDim.x){ float v=r[d]; row[d]=v; lsum+=v; }
    float mean = block_reduce_sum(lsum, sbuf) * (1.0f/DIMX);
    float lv = 0;
    for(int d=threadIdx.x; d<DIMX; d+=blockDim.x){ float dv=row[d]-mean; lv+=dv*dv; }
    float var = block_reduce_sum(lv, sbuf) * (1.0f/DIMX);
    float rstd = rsqrtf(var + 1e-5f);
    for(int d=threadIdx.x; d<DIMX; d+=blockDim.x)
        out[(long)tok*DIMX+d] = (row[d]-mean)*rstd*g[d] + b[d];
}

// ---------------- fused: kz = t1@tr_w2+b, K=softmax(6x6), pi_ev = pi@K ----------------
__global__ void k_trans(const float* __restrict__ t1, const float* __restrict__ w2,
                        const float* __restrict__ b2, const float* __restrict__ pi,
                        float* __restrict__ pi_ev){
    int tok = blockIdx.x;
    const float* a = t1 + (long)tok*(2*DIMX);
    float acc[36];
    #pragma unroll
    for(int j=0;j<36;j++) acc[j]=0.0f;
    for(int k=threadIdx.x; k<2*DIMX; k+=blockDim.x){
        float av = a[k];
        const float* wr = w2 + (long)k*36;
        #pragma unroll
        for(int j=0;j<36;j++) acc[j] += av*wr[j];
    }
    __shared__ float red[4*36];
    __shared__ float kz_s[36];
    __shared__ float K_s[36];
    int lane = threadIdx.x & 63, wid = threadIdx.x >> 6;
    #pragma unroll
    for(int j=0;j<36;j++){
        float v = acc[j];
        #pragma unroll
        for(int off=32;off>0;off>>=1) v += __shfl_down(v,off,64);
        if(lane==0) red[wid*36+j]=v;
    }
    __syncthreads();
    if(threadIdx.x<36)
        kz_s[threadIdx.x] = red[threadIdx.x]+red[36+threadIdx.x]+red[72+threadIdx.x]
                           +red[108+threadIdx.x] + b2[threadIdx.x];
    __syncthreads();
    if(threadIdx.x<SX){
        int s = threadIdx.x;
        float mx=-1e30f;
        for(int u=0;u<SX;u++) mx=fmaxf(mx,kz_s[s*SX+u]);
        float e[SX]; float sum=0;
        for(int u=0;u<SX;u++){ e[u]=expf(kz_s[s*SX+u]-mx); sum+=e[u]; }
        for(int u=0;u<SX;u++) K_s[s*SX+u]=e[u]/sum;
    }
    __syncthreads();
    if(threadIdx.x<SX){
        int u = threadIdx.x;
        float v=0;
        for(int s=0;s<SX;s++) v += pi[tok*SX+s]*K_s[s*SX+u];
        pi_ev[tok*SX+u]=v;
    }
}

// ---------------- fused: ev, pi update (softmax, top-2, renorm) + expert-list append ----------------
__global__ void k_pi_update(const float* __restrict__ mun, const float* __restrict__ ev_w,
                            const float* __restrict__ ev_b, const float* __restrict__ pi_ev,
                            float* __restrict__ pi, int* __restrict__ gidx, int* __restrict__ cnt){
    int tok = blockIdx.x;
    const float* r = mun + (long)tok*DIMX;
    float acc[SX] = {};
    for(int d=threadIdx.x; d<DIMX; d+=blockDim.x){
        float v = r[d];
        const float* w = ev_w + (long)d*SX;
        #pragma unroll
        for(int s=0;s<SX;s++) acc[s] += v*w[s];
    }
    __shared__ float red[4*SX];
    int lane = threadIdx.x & 63, wid = threadIdx.x >> 6;
    #pragma unroll
    for(int s=0;s<SX;s++){
        float v = acc[s];
        #pragma unroll
        for(int off=32;off>0;off>>=1) v += __shfl_down(v,off,64);
        if(lane==0) red[wid*SX+s]=v;
    }
    __syncthreads();
    if(threadIdx.x==0){
        float ev[SX], pn[SX];
        float mx=-1e30f;
        for(int s=0;s<SX;s++){
            ev[s] = (red[s]+red[SX+s]+red[2*SX+s]+red[3*SX+s] + ev_b[s]) * 2.0f;
            mx = fmaxf(mx, ev[s]);
        }
        float sum=0;
        for(int s=0;s<SX;s++){ ev[s]=expf(ev[s]-mx); sum+=ev[s]; }
        float psum=0;
        for(int s=0;s<SX;s++){ pn[s]=pi_ev[tok*SX+s]*(ev[s]/sum); psum+=pn[s]; }
        float inv = 1.0f/fmaxf(psum,1e-8f);
        for(int s=0;s<SX;s++) pn[s]*=inv;
        int i1=0; for(int s=1;s<SX;s++) if(pn[s]>pn[i1]) i1=s;
        int i2=-1;
        for(int s=0;s<SX;s++){ if(s==i1) continue; if(i2<0 || pn[s]>pn[i2]) i2=s; }
        float out[SX]; float s2=0;
        for(int s=0;s<SX;s++){ out[s]=(s==i1||s==i2)?pn[s]:0.0f; s2+=out[s]; }
        float inv2 = 1.0f/fmaxf(s2,1e-8f);
        for(int s=0;s<SX;s++) pi[tok*SX+s]=out[s]*inv2;
        #pragma unroll
        for(int k=0;k<2;k++){
            int si = (k==0)? i1 : i2;
            if(out[si]*inv2 > 0.0f){
                int pos = atomicAdd(&cnt[si], 1);
                gidx[si*BT + pos] = tok;
            }
        }
    }
}

// ---------------- fused attention ----------------
__global__ void k_attn(const float* __restrict__ q, const float* __restrict__ kk,
                       const float* __restrict__ vv, const float* __restrict__ pi,
                       const float* __restrict__ g3, const float* __restrict__ b3,
                       float* __restrict__ msg){
    const int offs[4] = {-2,-1,1,2};
    const float RSQ = 0.03608439182435161f;
    int tok = blockIdx.x;
    int b = tok / TX, t = tok % TX;
    const float* qr = q + (long)tok*DIMX;
    float sc[4] = {0,0,0,0};
    for(int d=threadIdx.x; d<DIMX; d+=blockDim.x){
        float qv = qr[d];
        #pragma unroll
        for(int o=0;o<4;o++){
            int tt = t + offs[o];
            if(tt>=0 && tt<TX) sc[o] += qv * kk[((long)(b*TX+tt))*DIMX + d];
        }
    }
    __shared__ float red[4*4];
    __shared__ float wts[4];
    int lane = threadIdx.x & 63, wid = threadIdx.x >> 6;
    #pragma unroll
    for(int o=0;o<4;o++){
        float v = sc[o];
        #pragma unroll
        for(int off=32;off>0;off>>=1) v += __shfl_down(v,off,64);
        if(lane==0) red[wid*4+o]=v;
    }
    __syncthreads();
    if(threadIdx.x==0){
        float s[4], mx=-1e30f;
        for(int o=0;o<4;o++){
            int tt = t + offs[o];
            s[o] = (tt>=0 && tt<TX) ? (red[o]+red[4+o]+red[8+o]+red[12+o])*RSQ : -1e9f;
            mx = fmaxf(mx, s[o]);
        }
        float sum=0;
        for(int o=0;o<4;o++){ s[o]=expf(s[o]-mx); sum+=s[o]; }
        for(int o=0;o<4;o++) wts[o]=s[o]/sum;
    }
    __syncthreads();
    float p3 = pi[tok*SX+3];
    __shared__ float row[DIMX];
    __shared__ float sbuf[4];
    float lsum = 0;
    for(int d=threadIdx.x; d<DIMX; d+=blockDim.x){
        float m = 0;
        #pragma unroll
        for(int o=0;o<4;o++){
            int tt = t + offs[o];
            if(tt>=0 && tt<TX) m += wts[o]*vv[((long)(b*TX+tt))*DIMX + d];
        }
        m *= p3;
        row[d] = m; lsum += m;
    }
    float mean = block_reduce_sum(lsum, sbuf) * (1.0f/DIMX);
    float lv = 0;
    for(int d=threadIdx.x; d<DIMX; d+=blockDim.x){ float dv=row[d]-mean; lv+=dv*dv; }
    float var = block_reduce_sum(lv, sbuf) * (1.0f/DIMX);
    float rstd = rsqrtf(var + 1e-5f);
    for(int d=threadIdx.x; d<DIMX; d+=blockDim.x)
        msg[(long)tok*DIMX+d] = (row[d]-mean)*rstd*g3[d] + b3[d];
}

// ---------------- fused write-update + ln(5) + add 0.1*so ----------------
__global__ void k_update(const float* __restrict__ dlamz, const float* __restrict__ mhat,
                         const float* __restrict__ muwn, const float* __restrict__ so,
                         const float* __restrict__ pi, float* __restrict__ mu,
                         float* __restrict__ lam,
                         const float* __restrict__ g5, const float* __restrict__ b5){
    int tok = blockIdx.x;
    float g = pi[tok*SX+4];
    __shared__ float row[DIMX];
    __shared__ float sbuf[4];
    float lsum = 0;
    for(int d=threadIdx.x; d<DIMX; d+=blockDim.x){
        long i = (long)tok*DIMX + d;
        float dl = g * softplus_f(dlamz[i]);
        float l  = lam[i];
        float ln_ = l + dl;
        float v = (l*muwn[i] + dl*mhat[i]) / ln_;
        lam[i] = ln_;
        row[d] = v; lsum += v;
    }
    float mean = block_reduce_sum(lsum, sbuf) * (1.0f/DIMX);
    float lv = 0;
    for(int d=threadIdx.x; d<DIMX; d+=blockDim.x){ float dv=row[d]-mean; lv+=dv*dv; }
    float var = block_reduce_sum(lv, sbuf) * (1.0f/DIMX);
    float rstd = rsqrtf(var + 1e-5f);
    for(int d=threadIdx.x; d<DIMX; d+=blockDim.x){
        long i = (long)tok*DIMX + d;
        mu[i] = (row[d]-mean)*rstd*g5[d] + b5[d] + 0.1f*so[i];
    }
}

extern "C" void kernel_launch(void* const* d_in, const int* in_sizes, int n_in,
                              void* d_out, int out_size, void* d_ws, size_t ws_size,
                              hipStream_t stream){
    const int*   x       = (const int*)  d_in[0];
    const float* emb_w   = (const float*)d_in[1];
    const float* pos_w   = (const float*)d_in[2];
    const float* mu_w    = (const float*)d_in[3];
    const float* mu_b    = (const float*)d_in[4];
    const float* lam_w   = (const float*)d_in[5];
    const float* lam_b   = (const float*)d_in[6];
    const float* tr_w1   = (const float*)d_in[7];
    const float* tr_b1   = (const float*)d_in[8];
    const float* tr_w2   = (const float*)d_in[9];
    const float* tr_b2   = (const float*)d_in[10];
    const float* bank_w1 = (const float*)d_in[11];
    const float* bank_b1 = (const float*)d_in[12];
    const float* bank_w2 = (const float*)d_in[13];
    const float* bank_b2 = (const float*)d_in[14];
    const float* ev_w    = (const float*)d_in[15];
    const float* ev_b    = (const float*)d_in[16];
    const float* rt_q    = (const float*)d_in[17];
    const float* rt_k    = (const float*)d_in[18];
    const float* rt_v    = (const float*)d_in[19];
    const float* wr_lam_w= (const float*)d_in[20];
    const float* wr_lam_b= (const float*)d_in[21];
    const float* wr_mu_w = (const float*)d_in[22];
    const float* wr_mu_b = (const float*)d_in[23];
    const float* ln_g    = (const float*)d_in[24];
    const float* ln_b    = (const float*)d_in[25];

    float* ws  = (float*)d_ws;
    float* h   = ws;                            // BT*DIMX
    float* mu  = h   + (long)BT*DIMX;           // BT*DIMX
    float* lam = mu  + (long)BT*DIMX;           // BT*DIMX
    float* mun = lam + (long)BT*DIMX;           // BT*DIMX
    float* so  = mun + (long)BT*DIMX;           // (BT+1)*DIMX
    float* t1  = so  + (long)(BT+1)*DIMX;       // BT*2*DIMX
    float* hbf = t1  + (long)BT*2*DIMX;         // BT*FFX floats (region)
    float* pi  = hbf + (long)BT*FFX;            // BT*SX
    float* piv = pi  + (long)BT*SX;             // BT*SX
    int*   cnt = (int*)(piv + (long)BT*SX);     // 8 ints
    int*   gidx= cnt + 8;                       // SX*BT ints
    __bf16* emb16 = (__bf16*)(gidx + SX*BT);    // VX*DIMX bf16
    // aliases (lifetimes disjoint)
    float* q     = t1;
    float* kk    = t1 + (long)BT*DIMX;
    float* vv    = h;
    float* msg   = hbf;
    float* dlamz = hbf + (long)BT*DIMX;
    float* mhat  = hbf + 2L*BT*DIMX;
    __bf16* hbh  = (__bf16*)hbf;                // BT*FFX bf16 (hi)
    __bf16* hbl  = hbh + (long)BT*FFX;          // BT*FFX bf16 (lo) — fits region exactly

    // split+transposed weights region (appended after emb16)
    __bf16* sp = emb16 + (long)VX*DIMX;
    __bf16* muw_h = sp;              sp += 768L*768;
    __bf16* muw_l = sp;              sp += 768L*768;
    __bf16* lamw_h= sp;              sp += 768L*768;
    __bf16* lamw_l= sp;              sp += 768L*768;
    __bf16* rtq_h = sp;              sp += 768L*768;
    __bf16* rtq_l = sp;              sp += 768L*768;
    __bf16* rtk_h = sp;              sp += 768L*768;
    __bf16* rtk_l = sp;              sp += 768L*768;
    __bf16* rtv_h = sp;              sp += 768L*768;
    __bf16* rtv_l = sp;              sp += 768L*768;
    __bf16* wrl_h = sp;              sp += 768L*768;
    __bf16* wrl_l = sp;              sp += 768L*768;
    __bf16* wrm_h = sp;              sp += 768L*768;
    __bf16* wrm_l = sp;              sp += 768L*768;
    __bf16* tw1_h = sp;              sp += 1536L*768;
    __bf16* tw1_l = sp;              sp += 1536L*768;
    __bf16* bw1_h = sp;              sp += 6L*3072*768;
    __bf16* bw1_l = sp;              sp += 6L*3072*768;
    __bf16* bw2_h = sp;              sp += 6L*768*3072;
    __bf16* bw2_l = sp;              sp += 6L*768*3072;
    size_t need = (size_t)((char*)sp - (char*)d_ws);
    bool use_mfma = ws_size >= need;

    dim3 blk(256);
    dim3 g768(DIMX/64, BT/64);

    k_embed<<<BT, blk, 0, stream>>>(x, emb_w, pos_w, h, pi);
    k_init_lists<<<(SX*BT+255)/256, blk, 0, stream>>>(gidx, cnt);
    k_cvt_bf16<<<(VX*DIMX/4+255)/256, blk, 0, stream>>>(emb_w, emb16, (long)VX*DIMX);

    if(use_mfma){
        // ---- one-time weight split+transpose ----
        k_tsplit<<<dim3(24,24), blk, 0, stream>>>(mu_w,     muw_h, muw_l, 768, 768);
        k_tsplit<<<dim3(24,24), blk, 0, stream>>>(lam_w,    lamw_h,lamw_l,768, 768);
        k_tsplit<<<dim3(24,24), blk, 0, stream>>>(rt_q,     rtq_h, rtq_l, 768, 768);
        k_tsplit<<<dim3(24,24), blk, 0, stream>>>(rt_k,     rtk_h, rtk_l, 768, 768);
        k_tsplit<<<dim3(24,24), blk, 0, stream>>>(rt_v,     rtv_h, rtv_l, 768, 768);
        k_tsplit<<<dim3(24,24), blk, 0, stream>>>(wr_lam_w, wrl_h, wrl_l, 768, 768);
        k_tsplit<<<dim3(24,24), blk, 0, stream>>>(wr_mu_w,  wrm_h, wrm_l, 768, 768);
        k_tsplit<<<dim3(24,48), blk, 0, stream>>>(tr_w1,    tw1_h, tw1_l, 768, 1536);
        for(int s=0;s<SX;s++){
            k_tsplit<<<dim3(24,96), blk, 0, stream>>>(bank_w1+(long)s*DIMX*FFX,
                bw1_h+(long)s*FFX*DIMX, bw1_l+(long)s*FFX*DIMX, 768, 3072);
            k_tsplit<<<dim3(96,24), blk, 0, stream>>>(bank_w2+(long)s*FFX*DIMX,
                bw2_h+(long)s*DIMX*FFX, bw2_l+(long)s*DIMX*FFX, 3072, 768);
        }
        k_gemm_mfma<64,128,0,0,0,0><<<dim3(6,32), blk, 0, stream>>>(
            h, nullptr,nullptr, muw_h, muw_l, mu_b, mu, nullptr,nullptr,
            nullptr,nullptr,nullptr,0, DIMX, DIMX);
        k_gemm_mfma<64,128,0,0,2,0><<<dim3(6,32), blk, 0, stream>>>(
            h, nullptr,nullptr, lamw_h, lamw_l, lam_b, lam, nullptr,nullptr,
            nullptr,nullptr,nullptr,0, DIMX, DIMX);
    } else {
        k_gemm_nn<0><<<g768, blk, 0, stream>>>(h, mu_w,  mu_b,  mu,  BT, DIMX, DIMX);
        k_gemm_nn<2><<<g768, blk, 0, stream>>>(h, lam_w, lam_b, lam, BT, DIMX, DIMX);
    }

    for(int step=0; step<3; step++){
        // transition MLP -> pi_ev
        if(use_mfma)
            k_gemm_mfma<64,128,0,0,1,0><<<dim3(12,32), blk, 0, stream>>>(
                mu, nullptr,nullptr, tw1_h, tw1_l, tr_b1, t1, nullptr,nullptr,
                nullptr,nullptr,nullptr,0, 2*DIMX, DIMX);
        else
            k_gemm_nn<1><<<dim3(2*DIMX/64, BT/64), blk, 0, stream>>>(mu, tr_w1, tr_b1, t1, BT, 2*DIMX, DIMX);
        k_trans<<<BT, blk, 0, stream>>>(t1, tr_w2, tr_b2, pi, piv);
        // bank MoE — gathered by live expert lists
        k_ln<<<BT, blk, 0, stream>>>(mu, mun, ln_g+0*DIMX, ln_b+0*DIMX);
        hipMemsetAsync(so, 0, (size_t)(BT+1)*DIMX*sizeof(float), stream);
        for(int s=0; s<SX; s++){
            if(use_mfma){
                k_gemm_mfma<128,128,1,0,1,1><<<dim3(FFX/128, BT/128), blk, 0, stream>>>(
                    mun, nullptr,nullptr, bw1_h+(long)s*FFX*DIMX, bw1_l+(long)s*FFX*DIMX,
                    bank_b1+(long)s*FFX, nullptr, hbh, hbl,
                    nullptr, gidx, cnt, s, FFX, DIMX);
                k_gemm_mfma<64,128,0,1,0,2><<<dim3(DIMX/128, BT/64), blk, 0, stream>>>(
                    nullptr, hbh, hbl, bw2_h+(long)s*DIMX*FFX, bw2_l+(long)s*DIMX*FFX,
                    bank_b2+(long)s*DIMX, so, nullptr,nullptr,
                    pi, gidx, cnt, s, DIMX, FFX);
            } else {
                k_gemm_g1<<<dim3(FFX/64, BT/64), blk, 0, stream>>>(
                    mun, bank_w1+(long)s*DIMX*FFX, bank_b1+(long)s*FFX, hbf, gidx, cnt, s, FFX, DIMX);
                k_gemm_g2<<<dim3(DIMX/64, BT/64), blk, 0, stream>>>(
                    hbf, bank_w2+(long)s*FFX*DIMX, bank_b2+(long)s*DIMX, so, pi, gidx, cnt, s, DIMX, FFX);
            }
        }
        k_ln<<<BT, blk, 0, stream>>>(so, so, ln_g+1*DIMX, ln_b+1*DIMX);
        // pi update + next step's expert lists
        k_fill_lists<<<(SX*BT+255)/256, blk, 0, stream>>>(gidx, cnt);
        k_pi_update<<<BT, blk, 0, stream>>>(mun, ev_w, ev_b, piv, pi, gidx, cnt);
        // routed attention
        k_ln<<<BT, blk, 0, stream>>>(mu, mun, ln_g+2*DIMX, ln_b+2*DIMX);
        if(use_mfma){
            k_gemm_mfma<64,128,0,0,0,0><<<dim3(6,32), blk, 0, stream>>>(
                mun, nullptr,nullptr, rtq_h, rtq_l, nullptr, q, nullptr,nullptr,
                nullptr,nullptr,nullptr,0, DIMX, DIMX);
            k_gemm_mfma<64,128,0,0,0,0><<<dim3(6,32), blk, 0, stream>>>(
                mun, nullptr,nullptr, rtk_h, rtk_l, nullptr, kk, nullptr,nullptr,
                nullptr,nullptr,nullptr,0, DIMX, DIMX);
            k_gemm_mfma<64,128,0,0,0,0><<<dim3(6,32), blk, 0, stream>>>(
                mun, nullptr,nullptr, rtv_h, rtv_l, nullptr, vv, nullptr,nullptr,
                nullptr,nullptr,nullptr,0, DIMX, DIMX);
        } else {
            k_gemm_nn<0><<<g768, blk, 0, stream>>>(mun, rt_q, nullptr, q,  BT, DIMX, DIMX);
            k_gemm_nn<0><<<g768, blk, 0, stream>>>(mun, rt_k, nullptr, kk, BT, DIMX, DIMX);
            k_gemm_nn<0><<<g768, blk, 0, stream>>>(mun, rt_v, nullptr, vv, BT, DIMX, DIMX);
        }
        k_attn<<<BT, blk, 0, stream>>>(q, kk, vv, pi, ln_g+3*DIMX, ln_b+3*DIMX, msg);
        // write update
        k_ln<<<BT, blk, 0, stream>>>(mu, mun, ln_g+4*DIMX, ln_b+4*DIMX);
        if(use_mfma){
            k_gemm_mfma<64,128,0,0,0,0><<<dim3(6,32), blk, 0, stream>>>(
                msg, nullptr,nullptr, wrl_h, wrl_l, wr_lam_b, dlamz, nullptr,nullptr,
                nullptr,nullptr,nullptr,0, DIMX, DIMX);
            k_gemm_mfma<64,128,0,0,0,0><<<dim3(6,32), blk, 0, stream>>>(
                msg, nullptr,nullptr, wrm_h, wrm_l, wr_mu_b, mhat, nullptr,nullptr,
                nullptr,nullptr,nullptr,0, DIMX, DIMX);
        } else {
            k_gemm_nn<0><<<g768, blk, 0, stream>>>(msg, wr_lam_w, wr_lam_b, dlamz, BT, DIMX, DIMX);
            k_gemm_nn<0><<<g768, blk, 0, stream>>>(msg, wr_mu_w,  wr_mu_b,  mhat,  BT, DIMX, DIMX);
        }
        k_update<<<BT, blk, 0, stream>>>(dlamz, mhat, mun, so, pi, mu, lam, ln_g+5*DIMX, ln_b+5*DIMX);
    }
    // final LN + logits (bf16 MFMA, grid swapped for B-tile L2 reuse)
    k_ln<<<BT, blk, 0, stream>>>(mu, mun, ln_g+6*DIMX, ln_b+6*DIMX);
    k_logits_mfma<<<dim3(BT/128, VX/128), blk, 0, stream>>>(mun, emb16, (float*)d_out,
                                                            0.03608439182435161f);
}

// Round 8
// 2602.878 us; speedup vs baseline: 2.1984x; 1.5771x over previous
//
#include <hip/hip_runtime.h>
#include <math.h>

#define DIMX 768
#define FFX  3072
#define SX   6
#define VX   32000
#define BX   2
#define TX   1024
#define BT   (BX*TX)
#define LDK  40   // LDS row stride (bf16 elems) for 32-wide K tiles, padded

typedef __bf16 bf16x8 __attribute__((ext_vector_type(8)));
typedef __bf16 bf16x4 __attribute__((ext_vector_type(4)));
typedef float  f32x4  __attribute__((ext_vector_type(4)));

__device__ __forceinline__ float gelu_f(float x){
    float x3 = x*x*x;
    return 0.5f*x*(1.0f + tanhf(0.7978845608028654f*(x + 0.044715f*x3)));
}
__device__ __forceinline__ float softplus_f(float x){
    return fmaxf(x,0.0f) + log1pf(expf(-fabsf(x)));
}

__device__ __forceinline__ float block_reduce_sum(float v, volatile float* sbuf){
    #pragma unroll
    for(int off=32; off>0; off>>=1) v += __shfl_down(v, off, 64);
    int wid = threadIdx.x >> 6, lane = threadIdx.x & 63;
    __syncthreads();
    if(lane==0) sbuf[wid] = v;
    __syncthreads();
    return sbuf[0]+sbuf[1]+sbuf[2]+sbuf[3];
}

// ---------------- embed + pi init ----------------
__global__ void k_embed(const int* __restrict__ x, const float* __restrict__ emb,
                        const float* __restrict__ pos, float* __restrict__ h,
                        float* __restrict__ pi){
    int tok = blockIdx.x;
    int t = tok % TX;
    int id = x[tok];
    const float* er = emb + (long)id*DIMX;
    const float* pr = pos + (long)t*DIMX;
    float* hr = h + (long)tok*DIMX;
    for(int d=threadIdx.x; d<DIMX; d+=blockDim.x) hr[d] = er[d] + pr[d];
    if(threadIdx.x < SX) pi[tok*SX+threadIdx.x] = (threadIdx.x==2)?1.0f:0.0f;
}

// ---------------- expert list init ----------------
__global__ void k_init_lists(int* __restrict__ gidx, int* __restrict__ cnt){
    int tid = blockIdx.x*blockDim.x + threadIdx.x;
    if(tid < SX*BT) gidx[tid] = (tid/BT == 2) ? (tid % BT) : BT;
    if(tid < SX) cnt[tid] = (tid==2) ? BT : 0;
}
__global__ void k_fill_lists(int* __restrict__ gidx, int* __restrict__ cnt){
    int tid = blockIdx.x*blockDim.x + threadIdx.x;
    if(tid < SX*BT) gidx[tid] = BT;
    if(tid < SX) cnt[tid] = 0;
}

// ---------------- fp32 -> bf16 elementwise ----------------
__global__ void k_cvt_bf16(const float* __restrict__ in, __bf16* __restrict__ out, long n){
    long i = ((long)blockIdx.x*blockDim.x + threadIdx.x)*4;
    if(i+3 < n){
        float4 v = *(const float4*)&in[i];
        bf16x4 o;
        o[0]=(__bf16)v.x; o[1]=(__bf16)v.y; o[2]=(__bf16)v.z; o[3]=(__bf16)v.w;
        *(bf16x4*)&out[i] = o;
    }
}

// ---------------- transpose + hi/lo split: in [K][N] fp32 -> out [N][K] bf16 hi/lo ----
__global__ __launch_bounds__(256) void k_tsplit(const float* __restrict__ in,
        __bf16* __restrict__ oh, __bf16* __restrict__ ol, int K, int N){
    __shared__ float t[32][33];
    int k0 = blockIdx.x*32, n0 = blockIdx.y*32;
    int tid = threadIdx.x;
    #pragma unroll
    for(int i=0;i<4;i++){
        int r = (tid>>5) + i*8, cc = tid & 31;
        t[r][cc] = in[(long)(k0+r)*N + n0 + cc];
    }
    __syncthreads();
    int r2 = tid & 31, q = tid >> 5;
    bf16x4 h4, l4;
    #pragma unroll
    for(int e=0;e<4;e++){
        float v = t[q*4+e][r2];
        __bf16 hv = (__bf16)v;
        h4[e] = hv;
        l4[e] = (__bf16)(v - (float)hv);
    }
    long o = (long)(n0 + r2)*K + k0 + q*4;
    *(bf16x4*)&oh[o] = h4;
    *(bf16x4*)&ol[o] = l4;
}

// ---------------- unified split-bf16 MFMA GEMM ----------------
// C = act(A@B + bias). A fp32 (split on the fly) or pre-split bf16 pairs.
// B pre-split+transposed [N][K] bf16 hi/lo. 3-pass Dekker: AhBh + AlBh + AhBl.
// GATHER: A rows via gidx. OUT: 0 fp32 store, 1 bf16 hi/lo store (compact, guarded),
// 2 scatter atomicAdd C[gid[m]] += pi*v. CMP: expert-batched via blockIdx.z with
// compact row offsets (prefix of cnt) and per-expert B/bias offsets.
template<int BM, int BN, int GATHER, int ASRC, int ACT, int OUT, int CMP>
__global__ __launch_bounds__(256) void k_gemm_mfma(
    const float* __restrict__ A,
    const __bf16* __restrict__ Ahg, const __bf16* __restrict__ Alg,
    const __bf16* __restrict__ Bh, const __bf16* __restrict__ Bl,
    const float* __restrict__ bias, float* __restrict__ C,
    __bf16* __restrict__ Ch, __bf16* __restrict__ Cl,
    const float* __restrict__ pi, const int* __restrict__ gidx,
    const int* __restrict__ cnt, int s_base, int N, int K, long bstride)
{
    int s = s_base + blockIdx.z;
    int bm = blockIdx.y * BM, bn = blockIdx.x * BN;
    int c = BT;
    const int* gid = nullptr;
    int off = 0;
    if(GATHER || OUT==2){
        c = cnt[s];
        if(bm >= c) return;
        gid = gidx + s*BT;
        if(CMP){ for(int u=0;u<s;u++) off += cnt[u]; }
    }
    if(CMP){
        Bh += (long)s*bstride;
        Bl += (long)s*bstride;
        if(bias) bias += (long)s*N;
    }

    __shared__ __bf16 AhS[BM*LDK];
    __shared__ __bf16 AlS[BM*LDK];
    __shared__ __bf16 BhS[BN*LDK];
    __shared__ __bf16 BlS[BN*LDK];

    int tid = threadIdx.x;
    int lane = tid & 63, wave = tid >> 6, ln = lane & 15, quad = lane >> 4;
    constexpr int WGM = BM/64;
    constexpr int WGN = 4/WGM;
    constexpr int WM  = BM/WGM;
    constexpr int WN  = BN/WGN;
    constexpr int MR  = WM/16;
    constexpr int NR  = WN/16;
    int wm = (wave/WGN)*WM, wn = (wave%WGN)*WN;

    f32x4 acc[MR][NR];
    #pragma unroll
    for(int i=0;i<MR;i++){
        #pragma unroll
        for(int j=0;j<NR;j++){
            f32x4 z = {0.0f,0.0f,0.0f,0.0f};
            acc[i][j] = z;
        }
    }

    constexpr int ACH = (BM*32/8)/256;
    constexpr int BCH = (BN*32/8)/256;
    long arow[ACH];
    #pragma unroll
    for(int i=0;i<ACH;i++){
        int row = (tid + 256*i) >> 2;
        int gr;
        if(GATHER){ int g = gid[bm + row]; gr = (g < BT) ? g : 0; }
        else gr = off + bm + row;
        arow[i] = (long)gr * K;
    }

    for(int k0=0; k0<K; k0+=32){
        #pragma unroll
        for(int i=0;i<ACH;i++){
            int idx = tid + 256*i;
            int row = idx >> 2, c8 = idx & 3;
            if(ASRC==0){
                const float* src = A + arow[i] + k0 + c8*8;
                float4 v0 = *(const float4*)src;
                float4 v1 = *(const float4*)(src+4);
                float vs[8] = {v0.x,v0.y,v0.z,v0.w,v1.x,v1.y,v1.z,v1.w};
                bf16x8 h8, l8;
                #pragma unroll
                for(int e=0;e<8;e++){
                    __bf16 hv = (__bf16)vs[e];
                    h8[e] = hv;
                    l8[e] = (__bf16)(vs[e] - (float)hv);
                }
                *(bf16x8*)&AhS[row*LDK + c8*8] = h8;
                *(bf16x8*)&AlS[row*LDK + c8*8] = l8;
            } else {
                *(bf16x8*)&AhS[row*LDK + c8*8] = *(const bf16x8*)&Ahg[arow[i] + k0 + c8*8];
                *(bf16x8*)&AlS[row*LDK + c8*8] = *(const bf16x8*)&Alg[arow[i] + k0 + c8*8];
            }
        }
        #pragma unroll
        for(int i=0;i<BCH;i++){
            int idx = tid + 256*i;
            int row = idx >> 2, c8 = idx & 3;
            long o = (long)(bn + row)*K + k0 + c8*8;
            *(bf16x8*)&BhS[row*LDK + c8*8] = *(const bf16x8*)&Bh[o];
            *(bf16x8*)&BlS[row*LDK + c8*8] = *(const bf16x8*)&Bl[o];
        }
        __syncthreads();
        bf16x8 ah[MR], al[MR], bh[NR], bl[NR];
        #pragma unroll
        for(int i=0;i<MR;i++){
            ah[i] = *(const bf16x8*)&AhS[(wm+i*16+ln)*LDK + quad*8];
            al[i] = *(const bf16x8*)&AlS[(wm+i*16+ln)*LDK + quad*8];
        }
        #pragma unroll
        for(int j=0;j<NR;j++){
            bh[j] = *(const bf16x8*)&BhS[(wn+j*16+ln)*LDK + quad*8];
            bl[j] = *(const bf16x8*)&BlS[(wn+j*16+ln)*LDK + quad*8];
        }
        #pragma unroll
        for(int i=0;i<MR;i++)
            #pragma unroll
            for(int j=0;j<NR;j++)
                acc[i][j] = __builtin_amdgcn_mfma_f32_16x16x32_bf16(ah[i], bh[j], acc[i][j], 0,0,0);
        #pragma unroll
        for(int i=0;i<MR;i++)
            #pragma unroll
            for(int j=0;j<NR;j++)
                acc[i][j] = __builtin_amdgcn_mfma_f32_16x16x32_bf16(al[i], bh[j], acc[i][j], 0,0,0);
        #pragma unroll
        for(int i=0;i<MR;i++)
            #pragma unroll
            for(int j=0;j<NR;j++)
                acc[i][j] = __builtin_amdgcn_mfma_f32_16x16x32_bf16(ah[i], bl[j], acc[i][j], 0,0,0);
        __syncthreads();
    }

    #pragma unroll
    for(int i=0;i<MR;i++){
        #pragma unroll
        for(int j=0;j<NR;j++){
            int n = bn + wn + j*16 + ln;
            float bv = bias ? bias[n] : 0.0f;
            #pragma unroll
            for(int r=0;r<4;r++){
                int ml = wm + i*16 + quad*4 + r;
                float v = acc[i][j][r] + bv;
                if(ACT==1) v = gelu_f(v);
                else if(ACT==2) v = softplus_f(v) + 0.1f;
                if(OUT==0){
                    C[(long)(bm+ml)*N + n] = v;
                } else if(OUT==1){
                    if(bm+ml < c){
                        long o = (long)(off + bm + ml)*N + n;
                        __bf16 hv = (__bf16)v;
                        Ch[o] = hv;
                        Cl[o] = (__bf16)(v - (float)hv);
                    }
                } else {
                    int m = bm + ml;
                    int tok = (m < c) ? gid[m] : BT;
                    float p = (m < c && tok < BT) ? pi[tok*SX + s] : 0.0f;
                    if(tok > BT) tok = BT;
                    atomicAdd(&C[(long)tok*N + n], p * v);
                }
            }
        }
    }
}

// ---------------- logits: bf16 MFMA NT GEMM, C = alpha * A @ B^T, XCD-swizzled ----------------
__global__ void k_logits_mfma(const __bf16* __restrict__ A, const __bf16* __restrict__ Bw,
                              float* __restrict__ C, float alpha){
    __shared__ __bf16 Ah[128*LDK];
    __shared__ __bf16 Bh[128*LDK];
    int tid = threadIdx.x;
    int wave = tid>>6, lane = tid&63, ln = lane&15, quad = lane>>4;
    // bijective XCD swizzle: nwg = 16*250 = 4000, 4000%8==0
    int orig = blockIdx.x + gridDim.x*blockIdx.y;   // HW dispatch-linear id
    int nid  = (orig & 7)*500 + (orig >> 3);
    int bm = (nid % 16)*128, bn = (nid / 16)*128;
    int wm = (wave>>1)*64, wn = (wave&1)*64;
    f32x4 zero = {0.0f,0.0f,0.0f,0.0f};
    f32x4 acc[4][4];
    #pragma unroll
    for(int i=0;i<4;i++)
        #pragma unroll
        for(int j=0;j<4;j++) acc[i][j] = zero;
    for(int k0=0; k0<DIMX; k0+=32){
        #pragma unroll
        for(int i=0;i<2;i++){
            int idx = tid + 256*i;
            int row = idx>>2, c8 = idx&3;
            *(bf16x8*)&Ah[row*LDK + c8*8] = *(const bf16x8*)&A[(long)(bm+row)*DIMX + k0 + c8*8];
        }
        #pragma unroll
        for(int i=0;i<2;i++){
            int idx = tid + 256*i;
            int row = idx>>2, c8 = idx&3;
            *(bf16x8*)&Bh[row*LDK + c8*8] = *(const bf16x8*)&Bw[(long)(bn+row)*DIMX + k0 + c8*8];
        }
        __syncthreads();
        bf16x8 af[4], bfr[4];
        #pragma unroll
        for(int i=0;i<4;i++) af[i]  = *(const bf16x8*)&Ah[(wm+i*16+ln)*LDK + quad*8];
        #pragma unroll
        for(int j=0;j<4;j++) bfr[j] = *(const bf16x8*)&Bh[(wn+j*16+ln)*LDK + quad*8];
        #pragma unroll
        for(int i=0;i<4;i++)
            #pragma unroll
            for(int j=0;j<4;j++)
                acc[i][j] = __builtin_amdgcn_mfma_f32_16x16x32_bf16(af[i], bfr[j], acc[i][j], 0,0,0);
        __syncthreads();
    }
    #pragma unroll
    for(int i=0;i<4;i++){
        #pragma unroll
        for(int j=0;j<4;j++){
            #pragma unroll
            for(int r=0;r<4;r++){
                int m = bm + wm + i*16 + quad*4 + r;
                int n = bn + wn + j*16 + ln;
                C[(long)m*VX + n] = alpha * acc[i][j][r];
            }
        }
    }
}

// ---------------- layernorm (single) ----------------
__global__ void k_ln(const float* __restrict__ in, float* __restrict__ out,
                     const float* __restrict__ g, const float* __restrict__ b){
    int tok = blockIdx.x;
    const float* r = in + (long)tok*DIMX;
    __shared__ float row[DIMX];
    __shared__ float sbuf[4];
    float lsum = 0;
    for(int d=threadIdx.x; d<DIMX; d+=blockDim.x){ float v=r[d]; row[d]=v; lsum+=v; }
    float mean = block_reduce_sum(lsum, sbuf) * (1.0f/DIMX);
    float lv = 0;
    for(int d=threadIdx.x; d<DIMX; d+=blockDim.x){ float dv=row[d]-mean; lv+=dv*dv; }
    float var = block_reduce_sum(lv, sbuf) * (1.0f/DIMX);
    float rstd = rsqrtf(var + 1e-5f);
    for(int d=threadIdx.x; d<DIMX; d+=blockDim.x)
        out[(long)tok*DIMX+d] = (row[d]-mean)*rstd*g[d] + b[d];
}

// ---------------- triple layernorm of mu: ln0 -> oA, ln2 -> oB, ln4 -> oC ----------------
__global__ void k_ln3(const float* __restrict__ in, float* __restrict__ oA,
                      float* __restrict__ oB, float* __restrict__ oC,
                      const float* __restrict__ lg, const float* __restrict__ lb){
    int tok = blockIdx.x;
    const float* r = in + (long)tok*DIMX;
    __shared__ float row[DIMX];
    __shared__ float sbuf[4];
    float lsum = 0;
    for(int d=threadIdx.x; d<DIMX; d+=blockDim.x){ float v=r[d]; row[d]=v; lsum+=v; }
    float mean = block_reduce_sum(lsum, sbuf) * (1.0f/DIMX);
    float lv = 0;
    for(int d=threadIdx.x; d<DIMX; d+=blockDim.x){ float dv=row[d]-mean; lv+=dv*dv; }
    float var = block_reduce_sum(lv, sbuf) * (1.0f/DIMX);
    float rstd = rsqrtf(var + 1e-5f);
    for(int d=threadIdx.x; d<DIMX; d+=blockDim.x){
        float nv = (row[d]-mean)*rstd;
        long i = (long)tok*DIMX + d;
        oA[i] = nv*lg[0*DIMX+d] + lb[0*DIMX+d];
        oB[i] = nv*lg[2*DIMX+d] + lb[2*DIMX+d];
        oC[i] = nv*lg[4*DIMX+d] + lb[4*DIMX+d];
    }
}

// ---------------- final layernorm -> bf16 ----------------
__global__ void k_ln_cvt(const float* __restrict__ in, __bf16* __restrict__ out,
                         const float* __restrict__ g, const float* __restrict__ b){
    int tok = blockIdx.x;
    const float* r = in + (long)tok*DIMX;
    __shared__ float row[DIMX];
    __shared__ float sbuf[4];
    float lsum = 0;
    for(int d=threadIdx.x; d<DIMX; d+=blockDim.x){ float v=r[d]; row[d]=v; lsum+=v; }
    float mean = block_reduce_sum(lsum, sbuf) * (1.0f/DIMX);
    float lv = 0;
    for(int d=threadIdx.x; d<DIMX; d+=blockDim.x){ float dv=row[d]-mean; lv+=dv*dv; }
    float var = block_reduce_sum(lv, sbuf) * (1.0f/DIMX);
    float rstd = rsqrtf(var + 1e-5f);
    for(int d=threadIdx.x; d<DIMX; d+=blockDim.x)
        out[(long)tok*DIMX+d] = (__bf16)((row[d]-mean)*rstd*g[d] + b[d]);
}

// ---------------- fused: kz = t1@tr_w2+b, K=softmax(6x6), pi_ev = pi@K ----------------
__global__ void k_trans(const float* __restrict__ t1, const float* __restrict__ w2,
                        const float* __restrict__ b2, const float* __restrict__ pi,
                        float* __restrict__ pi_ev){
    int tok = blockIdx.x;
    const float* a = t1 + (long)tok*(2*DIMX);
    float acc[36];
    #pragma unroll
    for(int j=0;j<36;j++) acc[j]=0.0f;
    for(int k=threadIdx.x; k<2*DIMX; k+=blockDim.x){
        float av = a[k];
        const float* wr = w2 + (long)k*36;
        #pragma unroll
        for(int j=0;j<36;j++) acc[j] += av*wr[j];
    }
    __shared__ float red[4*36];
    __shared__ float kz_s[36];
    __shared__ float K_s[36];
    int lane = threadIdx.x & 63, wid = threadIdx.x >> 6;
    #pragma unroll
    for(int j=0;j<36;j++){
        float v = acc[j];
        #pragma unroll
        for(int off=32;off>0;off>>=1) v += __shfl_down(v,off,64);
        if(lane==0) red[wid*36+j]=v;
    }
    __syncthreads();
    if(threadIdx.x<36)
        kz_s[threadIdx.x] = red[threadIdx.x]+red[36+threadIdx.x]+red[72+threadIdx.x]
                           +red[108+threadIdx.x] + b2[threadIdx.x];
    __syncthreads();
    if(threadIdx.x<SX){
        int s = threadIdx.x;
        float mx=-1e30f;
        for(int u=0;u<SX;u++) mx=fmaxf(mx,kz_s[s*SX+u]);
        float e[SX]; float sum=0;
        for(int u=0;u<SX;u++){ e[u]=expf(kz_s[s*SX+u]-mx); sum+=e[u]; }
        for(int u=0;u<SX;u++) K_s[s*SX+u]=e[u]/sum;
    }
    __syncthreads();
    if(threadIdx.x<SX){
        int u = threadIdx.x;
        float v=0;
        for(int s=0;s<SX;s++) v += pi[tok*SX+s]*K_s[s*SX+u];
        pi_ev[tok*SX+u]=v;
    }
}

// ---------------- fused: ev, pi update (softmax, top-2, renorm) + list append ----------------
__global__ void k_pi_update(const float* __restrict__ mun, const float* __restrict__ ev_w,
                            const float* __restrict__ ev_b, const float* __restrict__ pi_ev,
                            float* __restrict__ pi, int* __restrict__ gidx, int* __restrict__ cnt){
    int tok = blockIdx.x;
    const float* r = mun + (long)tok*DIMX;
    float acc[SX] = {};
    for(int d=threadIdx.x; d<DIMX; d+=blockDim.x){
        float v = r[d];
        const float* w = ev_w + (long)d*SX;
        #pragma unroll
        for(int s=0;s<SX;s++) acc[s] += v*w[s];
    }
    __shared__ float red[4*SX];
    int lane = threadIdx.x & 63, wid = threadIdx.x >> 6;
    #pragma unroll
    for(int s=0;s<SX;s++){
        float v = acc[s];
        #pragma unroll
        for(int off=32;off>0;off>>=1) v += __shfl_down(v,off,64);
        if(lane==0) red[wid*SX+s]=v;
    }
    __syncthreads();
    if(threadIdx.x==0){
        float ev[SX], pn[SX];
        float mx=-1e30f;
        for(int s=0;s<SX;s++){
            ev[s] = (red[s]+red[SX+s]+red[2*SX+s]+red[3*SX+s] + ev_b[s]) * 2.0f;
            mx = fmaxf(mx, ev[s]);
        }
        float sum=0;
        for(int s=0;s<SX;s++){ ev[s]=expf(ev[s]-mx); sum+=ev[s]; }
        float psum=0;
        for(int s=0;s<SX;s++){ pn[s]=pi_ev[tok*SX+s]*(ev[s]/sum); psum+=pn[s]; }
        float inv = 1.0f/fmaxf(psum,1e-8f);
        for(int s=0;s<SX;s++) pn[s]*=inv;
        int i1=0; for(int s=1;s<SX;s++) if(pn[s]>pn[i1]) i1=s;
        int i2=-1;
        for(int s=0;s<SX;s++){ if(s==i1) continue; if(i2<0 || pn[s]>pn[i2]) i2=s; }
        float out[SX]; float s2=0;
        for(int s=0;s<SX;s++){ out[s]=(s==i1||s==i2)?pn[s]:0.0f; s2+=out[s]; }
        float inv2 = 1.0f/fmaxf(s2,1e-8f);
        for(int s=0;s<SX;s++) pi[tok*SX+s]=out[s]*inv2;
        #pragma unroll
        for(int k=0;k<2;k++){
            int si = (k==0)? i1 : i2;
            if(out[si]*inv2 > 0.0f){
                int pos = atomicAdd(&cnt[si], 1);
                gidx[si*BT + pos] = tok;
            }
        }
    }
}

// ---------------- fused attention (qkv packed: [BT][2304] = q|k|v) ----------------
__global__ void k_attn(const float* __restrict__ qkv, const float* __restrict__ pi,
                       const float* __restrict__ g3, const float* __restrict__ b3,
                       float* __restrict__ msg){
    const int offs[4] = {-2,-1,1,2};
    const float RSQ = 0.03608439182435161f;
    int tok = blockIdx.x;
    int b = tok / TX, t = tok % TX;
    const float* qr = qkv + (long)tok*2304;
    float sc[4] = {0,0,0,0};
    for(int d=threadIdx.x; d<DIMX; d+=blockDim.x){
        float qv = qr[d];
        #pragma unroll
        for(int o=0;o<4;o++){
            int tt = t + offs[o];
            if(tt>=0 && tt<TX) sc[o] += qv * qkv[(long)(b*TX+tt)*2304 + 768 + d];
        }
    }
    __shared__ float red[4*4];
    __shared__ float wts[4];
    int lane = threadIdx.x & 63, wid = threadIdx.x >> 6;
    #pragma unroll
    for(int o=0;o<4;o++){
        float v = sc[o];
        #pragma unroll
        for(int off=32;off>0;off>>=1) v += __shfl_down(v,off,64);
        if(lane==0) red[wid*4+o]=v;
    }
    __syncthreads();
    if(threadIdx.x==0){
        float s[4], mx=-1e30f;
        for(int o=0;o<4;o++){
            int tt = t + offs[o];
            s[o] = (tt>=0 && tt<TX) ? (red[o]+red[4+o]+red[8+o]+red[12+o])*RSQ : -1e9f;
            mx = fmaxf(mx, s[o]);
        }
        float sum=0;
        for(int o=0;o<4;o++){ s[o]=expf(s[o]-mx); sum+=s[o]; }
        for(int o=0;o<4;o++) wts[o]=s[o]/sum;
    }
    __syncthreads();
    float p3 = pi[tok*SX+3];
    __shared__ float row[DIMX];
    __shared__ float sbuf[4];
    float lsum = 0;
    for(int d=threadIdx.x; d<DIMX; d+=blockDim.x){
        float m = 0;
        #pragma unroll
        for(int o=0;o<4;o++){
            int tt = t + offs[o];
            if(tt>=0 && tt<TX) m += wts[o]*qkv[(long)(b*TX+tt)*2304 + 1536 + d];
        }
        m *= p3;
        row[d] = m; lsum += m;
    }
    float mean = block_reduce_sum(lsum, sbuf) * (1.0f/DIMX);
    float lv = 0;
    for(int d=threadIdx.x; d<DIMX; d+=blockDim.x){ float dv=row[d]-mean; lv+=dv*dv; }
    float var = block_reduce_sum(lv, sbuf) * (1.0f/DIMX);
    float rstd = rsqrtf(var + 1e-5f);
    for(int d=threadIdx.x; d<DIMX; d+=blockDim.x)
        msg[(long)tok*DIMX+d] = (row[d]-mean)*rstd*g3[d] + b3[d];
}

// ---------------- fused write-update + ln(5) + add 0.1*so (wrout: [BT][1536] = dlamz|mhat) ----
__global__ void k_update(const float* __restrict__ wrout, const float* __restrict__ muwn,
                         const float* __restrict__ so, const float* __restrict__ pi,
                         float* __restrict__ mu, float* __restrict__ lam,
                         const float* __restrict__ g5, const float* __restrict__ b5){
    int tok = blockIdx.x;
    float g = pi[tok*SX+4];
    __shared__ float row[DIMX];
    __shared__ float sbuf[4];
    float lsum = 0;
    for(int d=threadIdx.x; d<DIMX; d+=blockDim.x){
        long i = (long)tok*DIMX + d;
        float dl = g * softplus_f(wrout[(long)tok*1536 + d]);
        float mh = wrout[(long)tok*1536 + 768 + d];
        float l  = lam[i];
        float ln_ = l + dl;
        float v = (l*muwn[i] + dl*mh) / ln_;
        lam[i] = ln_;
        row[d] = v; lsum += v;
    }
    float mean = block_reduce_sum(lsum, sbuf) * (1.0f/DIMX);
    float lv = 0;
    for(int d=threadIdx.x; d<DIMX; d+=blockDim.x){ float dv=row[d]-mean; lv+=dv*dv; }
    float var = block_reduce_sum(lv, sbuf) * (1.0f/DIMX);
    float rstd = rsqrtf(var + 1e-5f);
    for(int d=threadIdx.x; d<DIMX; d+=blockDim.x){
        long i = (long)tok*DIMX + d;
        mu[i] = (row[d]-mean)*rstd*g5[d] + b5[d] + 0.1f*so[i];
    }
}

extern "C" void kernel_launch(void* const* d_in, const int* in_sizes, int n_in,
                              void* d_out, int out_size, void* d_ws, size_t ws_size,
                              hipStream_t stream){
    const int*   x       = (const int*)  d_in[0];
    const float* emb_w   = (const float*)d_in[1];
    const float* pos_w   = (const float*)d_in[2];
    const float* mu_w    = (const float*)d_in[3];
    const float* mu_b    = (const float*)d_in[4];
    const float* lam_w   = (const float*)d_in[5];
    const float* lam_b   = (const float*)d_in[6];
    const float* tr_w1   = (const float*)d_in[7];
    const float* tr_b1   = (const float*)d_in[8];
    const float* tr_w2   = (const float*)d_in[9];
    const float* tr_b2   = (const float*)d_in[10];
    const float* bank_w1 = (const float*)d_in[11];
    const float* bank_b1 = (const float*)d_in[12];
    const float* bank_w2 = (const float*)d_in[13];
    const float* bank_b2 = (const float*)d_in[14];
    const float* ev_w    = (const float*)d_in[15];
    const float* ev_b    = (const float*)d_in[16];
    const float* rt_q    = (const float*)d_in[17];
    const float* rt_k    = (const float*)d_in[18];
    const float* rt_v    = (const float*)d_in[19];
    const float* wr_lam_w= (const float*)d_in[20];
    const float* wr_lam_b= (const float*)d_in[21];
    const float* wr_mu_w = (const float*)d_in[22];
    const float* wr_mu_b = (const float*)d_in[23];
    const float* ln_g    = (const float*)d_in[24];
    const float* ln_b    = (const float*)d_in[25];

    float* ws  = (float*)d_ws;
    float* h    = ws;                           // BT*DIMX   (embed; later munB)
    float* mu   = h   + (long)BT*DIMX;          // BT*DIMX
    float* lam  = mu  + (long)BT*DIMX;          // BT*DIMX
    float* mun  = lam + (long)BT*DIMX;          // BT*DIMX   (munA; final: bf16 A)
    float* so   = mun + (long)BT*DIMX;          // (BT+1)*DIMX
    float* t1   = so  + (long)(BT+1)*DIMX;      // BT*2*DIMX (t1; later munC in first half)
    float* hbf  = t1  + (long)BT*2*DIMX;        // BT*FFX    (seq hb | qkv+msg | wrout)
    float* pi   = hbf + (long)BT*FFX;           // BT*SX
    float* piv  = pi  + (long)BT*SX;            // BT*SX
    int*   cnt  = (int*)(piv + (long)BT*SX);    // 8 ints
    int*   gidx = cnt + 8;                      // SX*BT ints
    float* wrb  = (float*)(gidx + SX*BT);       // 1536 (wr_lam_b | wr_mu_b)
    __bf16* emb16 = (__bf16*)(wrb + 1536);      // VX*DIMX bf16

    // aliases (lifetimes disjoint within a step)
    float* munA = mun;
    float* munB = h;
    float* munC = t1;
    float* qkv  = hbf;                          // BT*2304
    float* msg  = hbf + (long)BT*2304;          // BT*DIMX
    float* wrout= hbf;                          // BT*1536 (qkv dead by then)
    __bf16* hbh = (__bf16*)hbf;                 // sequential-path hb hi
    __bf16* hbl = hbh + (long)BT*FFX;           // sequential-path hb lo

    // split+transposed weights (after emb16)
    __bf16* sp = emb16 + (long)VX*DIMX;
    __bf16* muw_h = sp;   sp += 768L*768;
    __bf16* muw_l = sp;   sp += 768L*768;
    __bf16* lamw_h= sp;   sp += 768L*768;
    __bf16* lamw_l= sp;   sp += 768L*768;
    __bf16* qkvc_h= sp;   sp += 2304L*768;
    __bf16* qkvc_l= sp;   sp += 2304L*768;
    __bf16* wrc_h = sp;   sp += 1536L*768;
    __bf16* wrc_l = sp;   sp += 1536L*768;
    __bf16* tw1_h = sp;   sp += 1536L*768;
    __bf16* tw1_l = sp;   sp += 1536L*768;
    __bf16* bw1_h = sp;   sp += 6L*3072*768;
    __bf16* bw1_l = sp;   sp += 6L*3072*768;
    __bf16* bw2_h = sp;   sp += 6L*768*3072;
    __bf16* bw2_l = sp;   sp += 6L*768*3072;
    // compact batched-MoE hidden buffer (4096 live rows + 64 pad)
    __bf16* hbXh = sp;    sp += 4160L*FFX;
    __bf16* hbXl = sp;    sp += 4160L*FFX;
    size_t need_batch = (size_t)((char*)sp - (char*)d_ws);
    bool use_batch = ws_size >= need_batch;

    dim3 blk(256);

    k_embed<<<BT, blk, 0, stream>>>(x, emb_w, pos_w, h, pi);
    k_init_lists<<<(SX*BT+255)/256, blk, 0, stream>>>(gidx, cnt);
    k_cvt_bf16<<<(VX*DIMX/4+255)/256, blk, 0, stream>>>(emb_w, emb16, (long)VX*DIMX);
    hipMemcpyAsync(wrb,      wr_lam_b, 768*sizeof(float), hipMemcpyDeviceToDevice, stream);
    hipMemcpyAsync(wrb+768,  wr_mu_b,  768*sizeof(float), hipMemcpyDeviceToDevice, stream);

    // ---- one-time weight split+transpose ----
    k_tsplit<<<dim3(24,24), blk, 0, stream>>>(mu_w,     muw_h, muw_l, 768, 768);
    k_tsplit<<<dim3(24,24), blk, 0, stream>>>(lam_w,    lamw_h,lamw_l,768, 768);
    k_tsplit<<<dim3(24,24), blk, 0, stream>>>(rt_q,     qkvc_h,            qkvc_l,            768, 768);
    k_tsplit<<<dim3(24,24), blk, 0, stream>>>(rt_k,     qkvc_h+768L*768,   qkvc_l+768L*768,   768, 768);
    k_tsplit<<<dim3(24,24), blk, 0, stream>>>(rt_v,     qkvc_h+1536L*768,  qkvc_l+1536L*768,  768, 768);
    k_tsplit<<<dim3(24,24), blk, 0, stream>>>(wr_lam_w, wrc_h,             wrc_l,             768, 768);
    k_tsplit<<<dim3(24,24), blk, 0, stream>>>(wr_mu_w,  wrc_h+768L*768,    wrc_l+768L*768,    768, 768);
    k_tsplit<<<dim3(24,48), blk, 0, stream>>>(tr_w1,    tw1_h, tw1_l, 768, 1536);
    for(int s=0;s<SX;s++){
        k_tsplit<<<dim3(24,96), blk, 0, stream>>>(bank_w1+(long)s*DIMX*FFX,
            bw1_h+(long)s*FFX*DIMX, bw1_l+(long)s*FFX*DIMX, 768, 3072);
        k_tsplit<<<dim3(96,24), blk, 0, stream>>>(bank_w2+(long)s*FFX*DIMX,
            bw2_h+(long)s*DIMX*FFX, bw2_l+(long)s*DIMX*FFX, 3072, 768);
    }

    // init GEMMs: mu = h@mu_w + b ; lam = softplus(h@lam_w + b)+0.1
    k_gemm_mfma<64,128,0,0,0,0,0><<<dim3(6,32), blk, 0, stream>>>(
        h, nullptr,nullptr, muw_h, muw_l, mu_b, mu, nullptr,nullptr,
        nullptr,nullptr,nullptr,0, DIMX, DIMX, 0);
    k_gemm_mfma<64,128,0,0,2,0,0><<<dim3(6,32), blk, 0, stream>>>(
        h, nullptr,nullptr, lamw_h, lamw_l, lam_b, lam, nullptr,nullptr,
        nullptr,nullptr,nullptr,0, DIMX, DIMX, 0);

    for(int step=0; step<3; step++){
        // transition MLP -> pi_ev
        k_gemm_mfma<64,128,0,0,1,0,0><<<dim3(12,32), blk, 0, stream>>>(
            mu, nullptr,nullptr, tw1_h, tw1_l, tr_b1, t1, nullptr,nullptr,
            nullptr,nullptr,nullptr,0, 2*DIMX, DIMX, 0);
        k_trans<<<BT, blk, 0, stream>>>(t1, tr_w2, tr_b2, pi, piv);
        // three LNs of mu in one pass (t1 is dead now -> munC lives there)
        k_ln3<<<BT, blk, 0, stream>>>(mu, munA, munB, munC, ln_g, ln_b);
        hipMemsetAsync(so, 0, (size_t)(BT+1)*DIMX*sizeof(float), stream);
        // bank MoE
        if(use_batch){
            k_gemm_mfma<128,128,1,0,1,1,1><<<dim3(FFX/128, BT/128, SX), blk, 0, stream>>>(
                munA, nullptr,nullptr, bw1_h, bw1_l, bank_b1, nullptr, hbXh, hbXl,
                nullptr, gidx, cnt, 0, FFX, DIMX, (long)FFX*DIMX);
            k_gemm_mfma<64,128,0,1,0,2,1><<<dim3(DIMX/128, BT/64, SX), blk, 0, stream>>>(
                nullptr, hbXh, hbXl, bw2_h, bw2_l, bank_b2, so, nullptr,nullptr,
                pi, gidx, cnt, 0, DIMX, FFX, (long)DIMX*FFX);
        } else {
            for(int s=0; s<SX; s++){
                k_gemm_mfma<128,128,1,0,1,1,0><<<dim3(FFX/128, BT/128), blk, 0, stream>>>(
                    munA, nullptr,nullptr, bw1_h+(long)s*FFX*DIMX, bw1_l+(long)s*FFX*DIMX,
                    bank_b1+(long)s*FFX, nullptr, hbh, hbl,
                    nullptr, gidx, cnt, s, FFX, DIMX, 0);
                k_gemm_mfma<64,128,0,1,0,2,0><<<dim3(DIMX/128, BT/64), blk, 0, stream>>>(
                    nullptr, hbh, hbl, bw2_h+(long)s*DIMX*FFX, bw2_l+(long)s*DIMX*FFX,
                    bank_b2+(long)s*DIMX, so, nullptr,nullptr,
                    pi, gidx, cnt, s, DIMX, FFX, 0);
            }
        }
        k_ln<<<BT, blk, 0, stream>>>(so, so, ln_g+1*DIMX, ln_b+1*DIMX);
        // pi update + next lists
        k_fill_lists<<<(SX*BT+255)/256, blk, 0, stream>>>(gidx, cnt);
        k_pi_update<<<BT, blk, 0, stream>>>(munA, ev_w, ev_b, piv, pi, gidx, cnt);
        // routed attention: fused q|k|v GEMM (N=2304)
        k_gemm_mfma<64,128,0,0,0,0,0><<<dim3(18,32), blk, 0, stream>>>(
            munB, nullptr,nullptr, qkvc_h, qkvc_l, nullptr, qkv, nullptr,nullptr,
            nullptr,nullptr,nullptr,0, 2304, DIMX, 0);
        k_attn<<<BT, blk, 0, stream>>>(qkv, pi, ln_g+3*DIMX, ln_b+3*DIMX, msg);
        // write update: fused wr_lam|wr_mu GEMM (N=1536)
        k_gemm_mfma<64,128,0,0,0,0,0><<<dim3(12,32), blk, 0, stream>>>(
            msg, nullptr,nullptr, wrc_h, wrc_l, wrb, wrout, nullptr,nullptr,
            nullptr,nullptr,nullptr,0, 1536, DIMX, 0);
        k_update<<<BT, blk, 0, stream>>>(wrout, munC, so, pi, mu, lam,
                                         ln_g+5*DIMX, ln_b+5*DIMX);
    }
    // final LN -> bf16, then logits (bf16 MFMA, XCD-swizzled)
    k_ln_cvt<<<BT, blk, 0, stream>>>(mu, (__bf16*)mun, ln_g+6*DIMX, ln_b+6*DIMX);
    k_logits_mfma<<<dim3(BT/128, VX/128), blk, 0, stream>>>((const __bf16*)mun, emb16,
                                                            (float*)d_out,
                                                            0.03608439182435161f);
}

// Round 9
// 2576.854 us; speedup vs baseline: 2.2207x; 1.0101x over previous
//
#include <hip/hip_runtime.h>
#include <math.h>

#define DIMX 768
#define FFX  3072
#define SX   6
#define VX   32000
#define BX   2
#define TX   1024
#define BT   (BX*TX)
#define LDK  40   // LDS row stride (bf16 elems) for 32-wide K tiles, padded

typedef __bf16 bf16x8 __attribute__((ext_vector_type(8)));
typedef __bf16 bf16x4 __attribute__((ext_vector_type(4)));
typedef float  f32x4  __attribute__((ext_vector_type(4)));

__device__ __forceinline__ float gelu_f(float x){
    float x3 = x*x*x;
    return 0.5f*x*(1.0f + tanhf(0.7978845608028654f*(x + 0.044715f*x3)));
}
__device__ __forceinline__ float softplus_f(float x){
    return fmaxf(x,0.0f) + log1pf(expf(-fabsf(x)));
}

__device__ __forceinline__ float block_reduce_sum(float v, volatile float* sbuf){
    #pragma unroll
    for(int off=32; off>0; off>>=1) v += __shfl_down(v, off, 64);
    int wid = threadIdx.x >> 6, lane = threadIdx.x & 63;
    __syncthreads();
    if(lane==0) sbuf[wid] = v;
    __syncthreads();
    return sbuf[0]+sbuf[1]+sbuf[2]+sbuf[3];
}

// ---------------- embed + pi init ----------------
__global__ void k_embed(const int* __restrict__ x, const float* __restrict__ emb,
                        const float* __restrict__ pos, float* __restrict__ h,
                        float* __restrict__ pi){
    int tok = blockIdx.x;
    int t = tok % TX;
    int id = x[tok];
    const float* er = emb + (long)id*DIMX;
    const float* pr = pos + (long)t*DIMX;
    float* hr = h + (long)tok*DIMX;
    for(int d=threadIdx.x; d<DIMX; d+=blockDim.x) hr[d] = er[d] + pr[d];
    if(threadIdx.x < SX) pi[tok*SX+threadIdx.x] = (threadIdx.x==2)?1.0f:0.0f;
}

// ---------------- expert list init ----------------
__global__ void k_init_lists(int* __restrict__ gidx, int* __restrict__ cnt){
    int tid = blockIdx.x*blockDim.x + threadIdx.x;
    if(tid < SX*BT) gidx[tid] = (tid/BT == 2) ? (tid % BT) : BT;
    if(tid < SX) cnt[tid] = (tid==2) ? BT : 0;
}
__global__ void k_fill_lists(int* __restrict__ gidx, int* __restrict__ cnt){
    int tid = blockIdx.x*blockDim.x + threadIdx.x;
    if(tid < SX*BT) gidx[tid] = BT;
    if(tid < SX) cnt[tid] = 0;
}

// ---------------- fp32 -> bf16 elementwise ----------------
__global__ void k_cvt_bf16(const float* __restrict__ in, __bf16* __restrict__ out, long n){
    long i = ((long)blockIdx.x*blockDim.x + threadIdx.x)*4;
    if(i+3 < n){
        float4 v = *(const float4*)&in[i];
        bf16x4 o;
        o[0]=(__bf16)v.x; o[1]=(__bf16)v.y; o[2]=(__bf16)v.z; o[3]=(__bf16)v.w;
        *(bf16x4*)&out[i] = o;
    }
}

// ---------------- transpose + hi/lo split: in [K][N] fp32 -> out [N][K] bf16 hi/lo ----
__global__ __launch_bounds__(256) void k_tsplit(const float* __restrict__ in,
        __bf16* __restrict__ oh, __bf16* __restrict__ ol, int K, int N){
    __shared__ float t[32][33];
    int k0 = blockIdx.x*32, n0 = blockIdx.y*32;
    int tid = threadIdx.x;
    #pragma unroll
    for(int i=0;i<4;i++){
        int r = (tid>>5) + i*8, cc = tid & 31;
        t[r][cc] = in[(long)(k0+r)*N + n0 + cc];
    }
    __syncthreads();
    int r2 = tid & 31, q = tid >> 5;
    bf16x4 h4, l4;
    #pragma unroll
    for(int e=0;e<4;e++){
        float v = t[q*4+e][r2];
        __bf16 hv = (__bf16)v;
        h4[e] = hv;
        l4[e] = (__bf16)(v - (float)hv);
    }
    long o = (long)(n0 + r2)*K + k0 + q*4;
    *(bf16x4*)&oh[o] = h4;
    *(bf16x4*)&ol[o] = l4;
}

// ---------------- unified split-bf16 MFMA GEMM ----------------
// C = act(A@B + bias). A fp32 (split on the fly) or pre-split bf16 pairs.
// B pre-split+transposed [N][K] bf16 hi/lo. 3-pass Dekker: AhBh + AlBh + AhBl.
// GATHER: A rows via gidx. OUT: 0 fp32 store, 1 bf16 hi/lo store (compact, guarded),
// 2 scatter atomicAdd C[gid[m]] += pi*v. CMP: expert-batched via blockIdx.z with
// compact row offsets (prefix of cnt) and per-expert B/bias offsets.
// KSPLIT: split-K (OUT==2 only — atomicAdd composes partials; bias gated to kc==0).
template<int BM, int BN, int GATHER, int ASRC, int ACT, int OUT, int CMP, int KSPLIT>
__global__ __launch_bounds__(256) void k_gemm_mfma(
    const float* __restrict__ A,
    const __bf16* __restrict__ Ahg, const __bf16* __restrict__ Alg,
    const __bf16* __restrict__ Bh, const __bf16* __restrict__ Bl,
    const float* __restrict__ bias, float* __restrict__ C,
    __bf16* __restrict__ Ch, __bf16* __restrict__ Cl,
    const float* __restrict__ pi, const int* __restrict__ gidx,
    const int* __restrict__ cnt, int s_base, int N, int K, long bstride)
{
    int zz = blockIdx.z;
    int s  = s_base + ((KSPLIT>1) ? (zz / KSPLIT) : zz);
    int kc = (KSPLIT>1) ? (zz % KSPLIT) : 0;
    int bm = blockIdx.y * BM, bn = blockIdx.x * BN;
    int c = BT;
    const int* gid = nullptr;
    int off = 0;
    if(GATHER || OUT==2){
        c = cnt[s];
        if(bm >= c) return;
        gid = gidx + s*BT;
        if(CMP){ for(int u=0;u<s;u++) off += cnt[u]; }
    }
    if(CMP){
        Bh += (long)s*bstride;
        Bl += (long)s*bstride;
        if(bias) bias += (long)s*N;
    }

    __shared__ __bf16 AhS[BM*LDK];
    __shared__ __bf16 AlS[BM*LDK];
    __shared__ __bf16 BhS[BN*LDK];
    __shared__ __bf16 BlS[BN*LDK];

    int tid = threadIdx.x;
    int lane = tid & 63, wave = tid >> 6, ln = lane & 15, quad = lane >> 4;
    constexpr int WGM = BM/64;
    constexpr int WGN = 4/WGM;
    constexpr int WM  = BM/WGM;
    constexpr int WN  = BN/WGN;
    constexpr int MR  = WM/16;
    constexpr int NR  = WN/16;
    int wm = (wave/WGN)*WM, wn = (wave%WGN)*WN;

    f32x4 acc[MR][NR];
    #pragma unroll
    for(int i=0;i<MR;i++){
        #pragma unroll
        for(int j=0;j<NR;j++){
            f32x4 z = {0.0f,0.0f,0.0f,0.0f};
            acc[i][j] = z;
        }
    }

    constexpr int ACH = (BM*32/8)/256;
    constexpr int BCH = (BN*32/8)/256;
    long arow[ACH];
    #pragma unroll
    for(int i=0;i<ACH;i++){
        int row = (tid + 256*i) >> 2;
        int gr;
        if(GATHER){ int g = gid[bm + row]; gr = (g < BT) ? g : 0; }
        else gr = off + bm + row;
        arow[i] = (long)gr * K;
    }

    int kchunk = K / KSPLIT;
    int kbeg = kc * kchunk, kend = kbeg + kchunk;
    for(int k0=kbeg; k0<kend; k0+=32){
        #pragma unroll
        for(int i=0;i<ACH;i++){
            int idx = tid + 256*i;
            int row = idx >> 2, c8 = idx & 3;
            if(ASRC==0){
                const float* src = A + arow[i] + k0 + c8*8;
                float4 v0 = *(const float4*)src;
                float4 v1 = *(const float4*)(src+4);
                float vs[8] = {v0.x,v0.y,v0.z,v0.w,v1.x,v1.y,v1.z,v1.w};
                bf16x8 h8, l8;
                #pragma unroll
                for(int e=0;e<8;e++){
                    __bf16 hv = (__bf16)vs[e];
                    h8[e] = hv;
                    l8[e] = (__bf16)(vs[e] - (float)hv);
                }
                *(bf16x8*)&AhS[row*LDK + c8*8] = h8;
                *(bf16x8*)&AlS[row*LDK + c8*8] = l8;
            } else {
                *(bf16x8*)&AhS[row*LDK + c8*8] = *(const bf16x8*)&Ahg[arow[i] + k0 + c8*8];
                *(bf16x8*)&AlS[row*LDK + c8*8] = *(const bf16x8*)&Alg[arow[i] + k0 + c8*8];
            }
        }
        #pragma unroll
        for(int i=0;i<BCH;i++){
            int idx = tid + 256*i;
            int row = idx >> 2, c8 = idx & 3;
            long o = (long)(bn + row)*K + k0 + c8*8;
            *(bf16x8*)&BhS[row*LDK + c8*8] = *(const bf16x8*)&Bh[o];
            *(bf16x8*)&BlS[row*LDK + c8*8] = *(const bf16x8*)&Bl[o];
        }
        __syncthreads();
        bf16x8 ah[MR], al[MR], bh[NR], bl[NR];
        #pragma unroll
        for(int i=0;i<MR;i++){
            ah[i] = *(const bf16x8*)&AhS[(wm+i*16+ln)*LDK + quad*8];
            al[i] = *(const bf16x8*)&AlS[(wm+i*16+ln)*LDK + quad*8];
        }
        #pragma unroll
        for(int j=0;j<NR;j++){
            bh[j] = *(const bf16x8*)&BhS[(wn+j*16+ln)*LDK + quad*8];
            bl[j] = *(const bf16x8*)&BlS[(wn+j*16+ln)*LDK + quad*8];
        }
        #pragma unroll
        for(int i=0;i<MR;i++)
            #pragma unroll
            for(int j=0;j<NR;j++)
                acc[i][j] = __builtin_amdgcn_mfma_f32_16x16x32_bf16(ah[i], bh[j], acc[i][j], 0,0,0);
        #pragma unroll
        for(int i=0;i<MR;i++)
            #pragma unroll
            for(int j=0;j<NR;j++)
                acc[i][j] = __builtin_amdgcn_mfma_f32_16x16x32_bf16(al[i], bh[j], acc[i][j], 0,0,0);
        #pragma unroll
        for(int i=0;i<MR;i++)
            #pragma unroll
            for(int j=0;j<NR;j++)
                acc[i][j] = __builtin_amdgcn_mfma_f32_16x16x32_bf16(ah[i], bl[j], acc[i][j], 0,0,0);
        __syncthreads();
    }

    #pragma unroll
    for(int i=0;i<MR;i++){
        #pragma unroll
        for(int j=0;j<NR;j++){
            int n = bn + wn + j*16 + ln;
            float bv = (bias && kc==0) ? bias[n] : 0.0f;
            #pragma unroll
            for(int r=0;r<4;r++){
                int ml = wm + i*16 + quad*4 + r;
                float v = acc[i][j][r] + bv;
                if(ACT==1) v = gelu_f(v);
                else if(ACT==2) v = softplus_f(v) + 0.1f;
                if(OUT==0){
                    C[(long)(bm+ml)*N + n] = v;
                } else if(OUT==1){
                    if(bm+ml < c){
                        long o = (long)(off + bm + ml)*N + n;
                        __bf16 hv = (__bf16)v;
                        Ch[o] = hv;
                        Cl[o] = (__bf16)(v - (float)hv);
                    }
                } else {
                    int m = bm + ml;
                    int tok = (m < c) ? gid[m] : BT;
                    float p = (m < c && tok < BT) ? pi[tok*SX + s] : 0.0f;
                    if(tok > BT) tok = BT;
                    atomicAdd(&C[(long)tok*N + n], p * v);
                }
            }
        }
    }
}

// ---------------- logits: bf16 MFMA NT GEMM, C = alpha * A @ B^T, XCD-swizzled ----------------
__global__ void k_logits_mfma(const __bf16* __restrict__ A, const __bf16* __restrict__ Bw,
                              float* __restrict__ C, float alpha){
    __shared__ __bf16 Ah[128*LDK];
    __shared__ __bf16 Bh[128*LDK];
    int tid = threadIdx.x;
    int wave = tid>>6, lane = tid&63, ln = lane&15, quad = lane>>4;
    // bijective XCD swizzle: nwg = 16*250 = 4000, 4000%8==0
    int orig = blockIdx.x + gridDim.x*blockIdx.y;   // HW dispatch-linear id
    int nid  = (orig & 7)*500 + (orig >> 3);
    int bm = (nid % 16)*128, bn = (nid / 16)*128;
    int wm = (wave>>1)*64, wn = (wave&1)*64;
    f32x4 zero = {0.0f,0.0f,0.0f,0.0f};
    f32x4 acc[4][4];
    #pragma unroll
    for(int i=0;i<4;i++)
        #pragma unroll
        for(int j=0;j<4;j++) acc[i][j] = zero;
    for(int k0=0; k0<DIMX; k0+=32){
        #pragma unroll
        for(int i=0;i<2;i++){
            int idx = tid + 256*i;
            int row = idx>>2, c8 = idx&3;
            *(bf16x8*)&Ah[row*LDK + c8*8] = *(const bf16x8*)&A[(long)(bm+row)*DIMX + k0 + c8*8];
        }
        #pragma unroll
        for(int i=0;i<2;i++){
            int idx = tid + 256*i;
            int row = idx>>2, c8 = idx&3;
            *(bf16x8*)&Bh[row*LDK + c8*8] = *(const bf16x8*)&Bw[(long)(bn+row)*DIMX + k0 + c8*8];
        }
        __syncthreads();
        bf16x8 af[4], bfr[4];
        #pragma unroll
        for(int i=0;i<4;i++) af[i]  = *(const bf16x8*)&Ah[(wm+i*16+ln)*LDK + quad*8];
        #pragma unroll
        for(int j=0;j<4;j++) bfr[j] = *(const bf16x8*)&Bh[(wn+j*16+ln)*LDK + quad*8];
        #pragma unroll
        for(int i=0;i<4;i++)
            #pragma unroll
            for(int j=0;j<4;j++)
                acc[i][j] = __builtin_amdgcn_mfma_f32_16x16x32_bf16(af[i], bfr[j], acc[i][j], 0,0,0);
        __syncthreads();
    }
    #pragma unroll
    for(int i=0;i<4;i++){
        #pragma unroll
        for(int j=0;j<4;j++){
            #pragma unroll
            for(int r=0;r<4;r++){
                int m = bm + wm + i*16 + quad*4 + r;
                int n = bn + wn + j*16 + ln;
                C[(long)m*VX + n] = alpha * acc[i][j][r];
            }
        }
    }
}

// ---------------- layernorm (single) ----------------
__global__ void k_ln(const float* __restrict__ in, float* __restrict__ out,
                     const float* __restrict__ g, const float* __restrict__ b){
    int tok = blockIdx.x;
    const float* r = in + (long)tok*DIMX;
    __shared__ float row[DIMX];
    __shared__ float sbuf[4];
    float lsum = 0;
    for(int d=threadIdx.x; d<DIMX; d+=blockDim.x){ float v=r[d]; row[d]=v; lsum+=v; }
    float mean = block_reduce_sum(lsum, sbuf) * (1.0f/DIMX);
    float lv = 0;
    for(int d=threadIdx.x; d<DIMX; d+=blockDim.x){ float dv=row[d]-mean; lv+=dv*dv; }
    float var = block_reduce_sum(lv, sbuf) * (1.0f/DIMX);
    float rstd = rsqrtf(var + 1e-5f);
    for(int d=threadIdx.x; d<DIMX; d+=blockDim.x)
        out[(long)tok*DIMX+d] = (row[d]-mean)*rstd*g[d] + b[d];
}

// ---------------- triple layernorm of mu: ln0 -> oA, ln2 -> oB, ln4 -> oC ----------------
__global__ void k_ln3(const float* __restrict__ in, float* __restrict__ oA,
                      float* __restrict__ oB, float* __restrict__ oC,
                      const float* __restrict__ lg, const float* __restrict__ lb){
    int tok = blockIdx.x;
    const float* r = in + (long)tok*DIMX;
    __shared__ float row[DIMX];
    __shared__ float sbuf[4];
    float lsum = 0;
    for(int d=threadIdx.x; d<DIMX; d+=blockDim.x){ float v=r[d]; row[d]=v; lsum+=v; }
    float mean = block_reduce_sum(lsum, sbuf) * (1.0f/DIMX);
    float lv = 0;
    for(int d=threadIdx.x; d<DIMX; d+=blockDim.x){ float dv=row[d]-mean; lv+=dv*dv; }
    float var = block_reduce_sum(lv, sbuf) * (1.0f/DIMX);
    float rstd = rsqrtf(var + 1e-5f);
    for(int d=threadIdx.x; d<DIMX; d+=blockDim.x){
        float nv = (row[d]-mean)*rstd;
        long i = (long)tok*DIMX + d;
        oA[i] = nv*lg[0*DIMX+d] + lb[0*DIMX+d];
        oB[i] = nv*lg[2*DIMX+d] + lb[2*DIMX+d];
        oC[i] = nv*lg[4*DIMX+d] + lb[4*DIMX+d];
    }
}

// ---------------- final layernorm -> bf16 ----------------
__global__ void k_ln_cvt(const float* __restrict__ in, __bf16* __restrict__ out,
                         const float* __restrict__ g, const float* __restrict__ b){
    int tok = blockIdx.x;
    const float* r = in + (long)tok*DIMX;
    __shared__ float row[DIMX];
    __shared__ float sbuf[4];
    float lsum = 0;
    for(int d=threadIdx.x; d<DIMX; d+=blockDim.x){ float v=r[d]; row[d]=v; lsum+=v; }
    float mean = block_reduce_sum(lsum, sbuf) * (1.0f/DIMX);
    float lv = 0;
    for(int d=threadIdx.x; d<DIMX; d+=blockDim.x){ float dv=row[d]-mean; lv+=dv*dv; }
    float var = block_reduce_sum(lv, sbuf) * (1.0f/DIMX);
    float rstd = rsqrtf(var + 1e-5f);
    for(int d=threadIdx.x; d<DIMX; d+=blockDim.x)
        out[(long)tok*DIMX+d] = (__bf16)((row[d]-mean)*rstd*g[d] + b[d]);
}

// ---------------- fused: kz = t1@tr_w2+b, K=softmax(6x6), pi_ev = pi@K ----------------
__global__ void k_trans(const float* __restrict__ t1, const float* __restrict__ w2,
                        const float* __restrict__ b2, const float* __restrict__ pi,
                        float* __restrict__ pi_ev){
    int tok = blockIdx.x;
    const float* a = t1 + (long)tok*(2*DIMX);
    float acc[36];
    #pragma unroll
    for(int j=0;j<36;j++) acc[j]=0.0f;
    for(int k=threadIdx.x; k<2*DIMX; k+=blockDim.x){
        float av = a[k];
        const float* wr = w2 + (long)k*36;
        #pragma unroll
        for(int j=0;j<36;j++) acc[j] += av*wr[j];
    }
    __shared__ float red[4*36];
    __shared__ float kz_s[36];
    __shared__ float K_s[36];
    int lane = threadIdx.x & 63, wid = threadIdx.x >> 6;
    #pragma unroll
    for(int j=0;j<36;j++){
        float v = acc[j];
        #pragma unroll
        for(int off=32;off>0;off>>=1) v += __shfl_down(v,off,64);
        if(lane==0) red[wid*36+j]=v;
    }
    __syncthreads();
    if(threadIdx.x<36)
        kz_s[threadIdx.x] = red[threadIdx.x]+red[36+threadIdx.x]+red[72+threadIdx.x]
                           +red[108+threadIdx.x] + b2[threadIdx.x];
    __syncthreads();
    if(threadIdx.x<SX){
        int s = threadIdx.x;
        float mx=-1e30f;
        for(int u=0;u<SX;u++) mx=fmaxf(mx,kz_s[s*SX+u]);
        float e[SX]; float sum=0;
        for(int u=0;u<SX;u++){ e[u]=expf(kz_s[s*SX+u]-mx); sum+=e[u]; }
        for(int u=0;u<SX;u++) K_s[s*SX+u]=e[u]/sum;
    }
    __syncthreads();
    if(threadIdx.x<SX){
        int u = threadIdx.x;
        float v=0;
        for(int s=0;s<SX;s++) v += pi[tok*SX+s]*K_s[s*SX+u];
        pi_ev[tok*SX+u]=v;
    }
}

// ---------------- fused: ev, pi update (softmax, top-2, renorm) + list append ----------------
__global__ void k_pi_update(const float* __restrict__ mun, const float* __restrict__ ev_w,
                            const float* __restrict__ ev_b, const float* __restrict__ pi_ev,
                            float* __restrict__ pi, int* __restrict__ gidx, int* __restrict__ cnt){
    int tok = blockIdx.x;
    const float* r = mun + (long)tok*DIMX;
    float acc[SX] = {};
    for(int d=threadIdx.x; d<DIMX; d+=blockDim.x){
        float v = r[d];
        const float* w = ev_w + (long)d*SX;
        #pragma unroll
        for(int s=0;s<SX;s++) acc[s] += v*w[s];
    }
    __shared__ float red[4*SX];
    int lane = threadIdx.x & 63, wid = threadIdx.x >> 6;
    #pragma unroll
    for(int s=0;s<SX;s++){
        float v = acc[s];
        #pragma unroll
        for(int off=32;off>0;off>>=1) v += __shfl_down(v,off,64);
        if(lane==0) red[wid*SX+s]=v;
    }
    __syncthreads();
    if(threadIdx.x==0){
        float ev[SX], pn[SX];
        float mx=-1e30f;
        for(int s=0;s<SX;s++){
            ev[s] = (red[s]+red[SX+s]+red[2*SX+s]+red[3*SX+s] + ev_b[s]) * 2.0f;
            mx = fmaxf(mx, ev[s]);
        }
        float sum=0;
        for(int s=0;s<SX;s++){ ev[s]=expf(ev[s]-mx); sum+=ev[s]; }
        float psum=0;
        for(int s=0;s<SX;s++){ pn[s]=pi_ev[tok*SX+s]*(ev[s]/sum); psum+=pn[s]; }
        float inv = 1.0f/fmaxf(psum,1e-8f);
        for(int s=0;s<SX;s++) pn[s]*=inv;
        int i1=0; for(int s=1;s<SX;s++) if(pn[s]>pn[i1]) i1=s;
        int i2=-1;
        for(int s=0;s<SX;s++){ if(s==i1) continue; if(i2<0 || pn[s]>pn[i2]) i2=s; }
        float out[SX]; float s2=0;
        for(int s=0;s<SX;s++){ out[s]=(s==i1||s==i2)?pn[s]:0.0f; s2+=out[s]; }
        float inv2 = 1.0f/fmaxf(s2,1e-8f);
        for(int s=0;s<SX;s++) pi[tok*SX+s]=out[s]*inv2;
        #pragma unroll
        for(int k=0;k<2;k++){
            int si = (k==0)? i1 : i2;
            if(out[si]*inv2 > 0.0f){
                int pos = atomicAdd(&cnt[si], 1);
                gidx[si*BT + pos] = tok;
            }
        }
    }
}

// ---------------- fused attention (qkv packed: [BT][2304] = q|k|v) ----------------
__global__ void k_attn(const float* __restrict__ qkv, const float* __restrict__ pi,
                       const float* __restrict__ g3, const float* __restrict__ b3,
                       float* __restrict__ msg){
    const int offs[4] = {-2,-1,1,2};
    const float RSQ = 0.03608439182435161f;
    int tok = blockIdx.x;
    int b = tok / TX, t = tok % TX;
    const float* qr = qkv + (long)tok*2304;
    float sc[4] = {0,0,0,0};
    for(int d=threadIdx.x; d<DIMX; d+=blockDim.x){
        float qv = qr[d];
        #pragma unroll
        for(int o=0;o<4;o++){
            int tt = t + offs[o];
            if(tt>=0 && tt<TX) sc[o] += qv * qkv[(long)(b*TX+tt)*2304 + 768 + d];
        }
    }
    __shared__ float red[4*4];
    __shared__ float wts[4];
    int lane = threadIdx.x & 63, wid = threadIdx.x >> 6;
    #pragma unroll
    for(int o=0;o<4;o++){
        float v = sc[o];
        #pragma unroll
        for(int off=32;off>0;off>>=1) v += __shfl_down(v,off,64);
        if(lane==0) red[wid*4+o]=v;
    }
    __syncthreads();
    if(threadIdx.x==0){
        float s[4], mx=-1e30f;
        for(int o=0;o<4;o++){
            int tt = t + offs[o];
            s[o] = (tt>=0 && tt<TX) ? (red[o]+red[4+o]+red[8+o]+red[12+o])*RSQ : -1e9f;
            mx = fmaxf(mx, s[o]);
        }
        float sum=0;
        for(int o=0;o<4;o++){ s[o]=expf(s[o]-mx); sum+=s[o]; }
        for(int o=0;o<4;o++) wts[o]=s[o]/sum;
    }
    __syncthreads();
    float p3 = pi[tok*SX+3];
    __shared__ float row[DIMX];
    __shared__ float sbuf[4];
    float lsum = 0;
    for(int d=threadIdx.x; d<DIMX; d+=blockDim.x){
        float m = 0;
        #pragma unroll
        for(int o=0;o<4;o++){
            int tt = t + offs[o];
            if(tt>=0 && tt<TX) m += wts[o]*qkv[(long)(b*TX+tt)*2304 + 1536 + d];
        }
        m *= p3;
        row[d] = m; lsum += m;
    }
    float mean = block_reduce_sum(lsum, sbuf) * (1.0f/DIMX);
    float lv = 0;
    for(int d=threadIdx.x; d<DIMX; d+=blockDim.x){ float dv=row[d]-mean; lv+=dv*dv; }
    float var = block_reduce_sum(lv, sbuf) * (1.0f/DIMX);
    float rstd = rsqrtf(var + 1e-5f);
    for(int d=threadIdx.x; d<DIMX; d+=blockDim.x)
        msg[(long)tok*DIMX+d] = (row[d]-mean)*rstd*g3[d] + b3[d];
}

// ---------------- fused write-update + ln(5) + add 0.1*so (wrout: [BT][1536] = dlamz|mhat) ----
__global__ void k_update(const float* __restrict__ wrout, const float* __restrict__ muwn,
                         const float* __restrict__ so, const float* __restrict__ pi,
                         float* __restrict__ mu, float* __restrict__ lam,
                         const float* __restrict__ g5, const float* __restrict__ b5){
    int tok = blockIdx.x;
    float g = pi[tok*SX+4];
    __shared__ float row[DIMX];
    __shared__ float sbuf[4];
    float lsum = 0;
    for(int d=threadIdx.x; d<DIMX; d+=blockDim.x){
        long i = (long)tok*DIMX + d;
        float dl = g * softplus_f(wrout[(long)tok*1536 + d]);
        float mh = wrout[(long)tok*1536 + 768 + d];
        float l  = lam[i];
        float ln_ = l + dl;
        float v = (l*muwn[i] + dl*mh) / ln_;
        lam[i] = ln_;
        row[d] = v; lsum += v;
    }
    float mean = block_reduce_sum(lsum, sbuf) * (1.0f/DIMX);
    float lv = 0;
    for(int d=threadIdx.x; d<DIMX; d+=blockDim.x){ float dv=row[d]-mean; lv+=dv*dv; }
    float var = block_reduce_sum(lv, sbuf) * (1.0f/DIMX);
    float rstd = rsqrtf(var + 1e-5f);
    for(int d=threadIdx.x; d<DIMX; d+=blockDim.x){
        long i = (long)tok*DIMX + d;
        mu[i] = (row[d]-mean)*rstd*g5[d] + b5[d] + 0.1f*so[i];
    }
}

extern "C" void kernel_launch(void* const* d_in, const int* in_sizes, int n_in,
                              void* d_out, int out_size, void* d_ws, size_t ws_size,
                              hipStream_t stream){
    const int*   x       = (const int*)  d_in[0];
    const float* emb_w   = (const float*)d_in[1];
    const float* pos_w   = (const float*)d_in[2];
    const float* mu_w    = (const float*)d_in[3];
    const float* mu_b    = (const float*)d_in[4];
    const float* lam_w   = (const float*)d_in[5];
    const float* lam_b   = (const float*)d_in[6];
    const float* tr_w1   = (const float*)d_in[7];
    const float* tr_b1   = (const float*)d_in[8];
    const float* tr_w2   = (const float*)d_in[9];
    const float* tr_b2   = (const float*)d_in[10];
    const float* bank_w1 = (const float*)d_in[11];
    const float* bank_b1 = (const float*)d_in[12];
    const float* bank_w2 = (const float*)d_in[13];
    const float* bank_b2 = (const float*)d_in[14];
    const float* ev_w    = (const float*)d_in[15];
    const float* ev_b    = (const float*)d_in[16];
    const float* rt_q    = (const float*)d_in[17];
    const float* rt_k    = (const float*)d_in[18];
    const float* rt_v    = (const float*)d_in[19];
    const float* wr_lam_w= (const float*)d_in[20];
    const float* wr_lam_b= (const float*)d_in[21];
    const float* wr_mu_w = (const float*)d_in[22];
    const float* wr_mu_b = (const float*)d_in[23];
    const float* ln_g    = (const float*)d_in[24];
    const float* ln_b    = (const float*)d_in[25];

    float* ws  = (float*)d_ws;
    float* h    = ws;                           // BT*DIMX   (embed; later munB)
    float* mu   = h   + (long)BT*DIMX;          // BT*DIMX
    float* lam  = mu  + (long)BT*DIMX;          // BT*DIMX
    float* mun  = lam + (long)BT*DIMX;          // BT*DIMX   (munA; final: bf16 A)
    float* so   = mun + (long)BT*DIMX;          // (BT+1)*DIMX
    float* t1   = so  + (long)(BT+1)*DIMX;      // BT*2*DIMX (t1; later munC in first half)
    float* hbf  = t1  + (long)BT*2*DIMX;        // BT*FFX    (seq hb | qkv+msg | wrout)
    float* pi   = hbf + (long)BT*FFX;           // BT*SX
    float* piv  = pi  + (long)BT*SX;            // BT*SX
    int*   cnt  = (int*)(piv + (long)BT*SX);    // 8 ints
    int*   gidx = cnt + 8;                      // SX*BT ints
    float* wrb  = (float*)(gidx + SX*BT);       // 1536 (wr_lam_b | wr_mu_b)
    __bf16* emb16 = (__bf16*)(wrb + 1536);      // VX*DIMX bf16

    // aliases (lifetimes disjoint within a step)
    float* munA = mun;
    float* munB = h;
    float* munC = t1;
    float* qkv  = hbf;                          // BT*2304
    float* msg  = hbf + (long)BT*2304;          // BT*DIMX
    float* wrout= hbf;                          // BT*1536 (qkv dead by then)
    __bf16* hbh = (__bf16*)hbf;                 // sequential-path hb hi
    __bf16* hbl = hbh + (long)BT*FFX;           // sequential-path hb lo

    // split+transposed weights (after emb16)
    __bf16* sp = emb16 + (long)VX*DIMX;
    __bf16* muw_h = sp;   sp += 768L*768;
    __bf16* muw_l = sp;   sp += 768L*768;
    __bf16* lamw_h= sp;   sp += 768L*768;
    __bf16* lamw_l= sp;   sp += 768L*768;
    __bf16* qkvc_h= sp;   sp += 2304L*768;
    __bf16* qkvc_l= sp;   sp += 2304L*768;
    __bf16* wrc_h = sp;   sp += 1536L*768;
    __bf16* wrc_l = sp;   sp += 1536L*768;
    __bf16* tw1_h = sp;   sp += 1536L*768;
    __bf16* tw1_l = sp;   sp += 1536L*768;
    __bf16* bw1_h = sp;   sp += 6L*3072*768;
    __bf16* bw1_l = sp;   sp += 6L*3072*768;
    __bf16* bw2_h = sp;   sp += 6L*768*3072;
    __bf16* bw2_l = sp;   sp += 6L*768*3072;
    // compact batched-MoE hidden buffer (4096 live rows + 64 pad)
    __bf16* hbXh = sp;    sp += 4160L*FFX;
    __bf16* hbXl = sp;    sp += 4160L*FFX;
    size_t need_batch = (size_t)((char*)sp - (char*)d_ws);
    bool use_batch = ws_size >= need_batch;

    dim3 blk(256);

    k_embed<<<BT, blk, 0, stream>>>(x, emb_w, pos_w, h, pi);
    k_init_lists<<<(SX*BT+255)/256, blk, 0, stream>>>(gidx, cnt);
    k_cvt_bf16<<<(VX*DIMX/4+255)/256, blk, 0, stream>>>(emb_w, emb16, (long)VX*DIMX);
    hipMemcpyAsync(wrb,      wr_lam_b, 768*sizeof(float), hipMemcpyDeviceToDevice, stream);
    hipMemcpyAsync(wrb+768,  wr_mu_b,  768*sizeof(float), hipMemcpyDeviceToDevice, stream);

    // ---- one-time weight split+transpose ----
    k_tsplit<<<dim3(24,24), blk, 0, stream>>>(mu_w,     muw_h, muw_l, 768, 768);
    k_tsplit<<<dim3(24,24), blk, 0, stream>>>(lam_w,    lamw_h,lamw_l,768, 768);
    k_tsplit<<<dim3(24,24), blk, 0, stream>>>(rt_q,     qkvc_h,            qkvc_l,            768, 768);
    k_tsplit<<<dim3(24,24), blk, 0, stream>>>(rt_k,     qkvc_h+768L*768,   qkvc_l+768L*768,   768, 768);
    k_tsplit<<<dim3(24,24), blk, 0, stream>>>(rt_v,     qkvc_h+1536L*768,  qkvc_l+1536L*768,  768, 768);
    k_tsplit<<<dim3(24,24), blk, 0, stream>>>(wr_lam_w, wrc_h,             wrc_l,             768, 768);
    k_tsplit<<<dim3(24,24), blk, 0, stream>>>(wr_mu_w,  wrc_h+768L*768,    wrc_l+768L*768,    768, 768);
    k_tsplit<<<dim3(24,48), blk, 0, stream>>>(tr_w1,    tw1_h, tw1_l, 768, 1536);
    for(int s=0;s<SX;s++){
        k_tsplit<<<dim3(24,96), blk, 0, stream>>>(bank_w1+(long)s*DIMX*FFX,
            bw1_h+(long)s*FFX*DIMX, bw1_l+(long)s*FFX*DIMX, 768, 3072);
        k_tsplit<<<dim3(96,24), blk, 0, stream>>>(bank_w2+(long)s*FFX*DIMX,
            bw2_h+(long)s*DIMX*FFX, bw2_l+(long)s*DIMX*FFX, 3072, 768);
    }

    // init GEMMs: mu = h@mu_w + b ; lam = softplus(h@lam_w + b)+0.1
    k_gemm_mfma<64,128,0,0,0,0,0,1><<<dim3(6,32), blk, 0, stream>>>(
        h, nullptr,nullptr, muw_h, muw_l, mu_b, mu, nullptr,nullptr,
        nullptr,nullptr,nullptr,0, DIMX, DIMX, 0);
    k_gemm_mfma<64,128,0,0,2,0,0,1><<<dim3(6,32), blk, 0, stream>>>(
        h, nullptr,nullptr, lamw_h, lamw_l, lam_b, lam, nullptr,nullptr,
        nullptr,nullptr,nullptr,0, DIMX, DIMX, 0);

    for(int step=0; step<3; step++){
        // transition MLP -> pi_ev
        k_gemm_mfma<64,128,0,0,1,0,0,1><<<dim3(12,32), blk, 0, stream>>>(
            mu, nullptr,nullptr, tw1_h, tw1_l, tr_b1, t1, nullptr,nullptr,
            nullptr,nullptr,nullptr,0, 2*DIMX, DIMX, 0);
        k_trans<<<BT, blk, 0, stream>>>(t1, tr_w2, tr_b2, pi, piv);
        // three LNs of mu in one pass (t1 is dead now -> munC lives there)
        k_ln3<<<BT, blk, 0, stream>>>(mu, munA, munB, munC, ln_g, ln_b);
        hipMemsetAsync(so, 0, (size_t)(BT+1)*DIMX*sizeof(float), stream);
        // bank MoE
        if(use_batch){
            k_gemm_mfma<128,128,1,0,1,1,1,1><<<dim3(FFX/128, BT/128, SX), blk, 0, stream>>>(
                munA, nullptr,nullptr, bw1_h, bw1_l, bank_b1, nullptr, hbXh, hbXl,
                nullptr, gidx, cnt, 0, FFX, DIMX, (long)FFX*DIMX);
            // split-K x4: z = expert*4 + kchunk; atomicAdd composes partials, bias at kc==0
            k_gemm_mfma<64,128,0,1,0,2,1,4><<<dim3(DIMX/128, BT/64, SX*4), blk, 0, stream>>>(
                nullptr, hbXh, hbXl, bw2_h, bw2_l, bank_b2, so, nullptr,nullptr,
                pi, gidx, cnt, 0, DIMX, FFX, (long)DIMX*FFX);
        } else {
            for(int s=0; s<SX; s++){
                k_gemm_mfma<128,128,1,0,1,1,0,1><<<dim3(FFX/128, BT/128), blk, 0, stream>>>(
                    munA, nullptr,nullptr, bw1_h+(long)s*FFX*DIMX, bw1_l+(long)s*FFX*DIMX,
                    bank_b1+(long)s*FFX, nullptr, hbh, hbl,
                    nullptr, gidx, cnt, s, FFX, DIMX, 0);
                k_gemm_mfma<64,128,0,1,0,2,0,1><<<dim3(DIMX/128, BT/64), blk, 0, stream>>>(
                    nullptr, hbh, hbl, bw2_h+(long)s*DIMX*FFX, bw2_l+(long)s*DIMX*FFX,
                    bank_b2+(long)s*DIMX, so, nullptr,nullptr,
                    pi, gidx, cnt, s, DIMX, FFX, 0);
            }
        }
        k_ln<<<BT, blk, 0, stream>>>(so, so, ln_g+1*DIMX, ln_b+1*DIMX);
        // pi update + next lists
        k_fill_lists<<<(SX*BT+255)/256, blk, 0, stream>>>(gidx, cnt);
        k_pi_update<<<BT, blk, 0, stream>>>(munA, ev_w, ev_b, piv, pi, gidx, cnt);
        // routed attention: fused q|k|v GEMM (N=2304)
        k_gemm_mfma<64,128,0,0,0,0,0,1><<<dim3(18,32), blk, 0, stream>>>(
            munB, nullptr,nullptr, qkvc_h, qkvc_l, nullptr, qkv, nullptr,nullptr,
            nullptr,nullptr,nullptr,0, 2304, DIMX, 0);
        k_attn<<<BT, blk, 0, stream>>>(qkv, pi, ln_g+3*DIMX, ln_b+3*DIMX, msg);
        // write update: fused wr_lam|wr_mu GEMM (N=1536)
        k_gemm_mfma<64,128,0,0,0,0,0,1><<<dim3(12,32), blk, 0, stream>>>(
            msg, nullptr,nullptr, wrc_h, wrc_l, wrb, wrout, nullptr,nullptr,
            nullptr,nullptr,nullptr,0, 1536, DIMX, 0);
        k_update<<<BT, blk, 0, stream>>>(wrout, munC, so, pi, mu, lam,
                                         ln_g+5*DIMX, ln_b+5*DIMX);
    }
    // final LN -> bf16, then logits (bf16 MFMA, XCD-swizzled)
    k_ln_cvt<<<BT, blk, 0, stream>>>(mu, (__bf16*)mun, ln_g+6*DIMX, ln_b+6*DIMX);
    k_logits_mfma<<<dim3(BT/128, VX/128), blk, 0, stream>>>((const __bf16*)mun, emb16,
                                                            (float*)d_out,
                                                            0.03608439182435161f);
}